// Round 13
// baseline (276.271 us; speedup 1.0000x reference)
//
#include <hip/hip_runtime.h>
#include <math.h>

#define N_NODES 1024
#define HDIM 128
#define EDGES 65536
#define LAYERS 6

typedef __attribute__((ext_vector_type(8))) short bf16x8;
typedef __attribute__((ext_vector_type(4))) float f32x4;

// workspace float offsets
#define OFF_H     0
#define OFF_Q     131072
#define OFF_K     262144       // bf16 k [1024][128] (as short*)
#define OFF_V     393216       // bf16 v [1024][128] (as short*)
#define OFF_SKP   524288
#define OFF_G     655360       // src_csr (int E) + ea_csr (float E)
#define OFF_SS    917504
#define OFF_EA    920576
#define OFF_CVEC  986112
#define OFF_INT   986240
#define OFF_M     1054912      // fp32 M [128 k][16384 n], n = m*128 + l  (m-outer!)
#define OFF_U     3152064      // bf16 U [1024 i][16384 n]
#define OFF_MT    11540672     // bf16 Mt [16384 n][128 k]
#define OFF_HB    12589248     // bf16 hb [1024][128]
#define OFF_WB    12654912     // bf16 transposed weights + Wm1T

#define WM1T_OFF  786432       // short offset of Wm1T inside WT

__device__ __forceinline__ float silu_f(float x) { return x / (1.f + expf(-x)); }
__device__ __forceinline__ float frcp(float x) { return __builtin_amdgcn_rcpf(x); }

__device__ __forceinline__ unsigned short f2bf(float f) {
    unsigned int u = __float_as_uint(f);
    u += 0x7FFFu + ((u >> 16) & 1u);
    return (unsigned short)(u >> 16);
}
__device__ __forceinline__ float bf2f(unsigned short s) {
    return __uint_as_float(((unsigned int)s) << 16);
}

// ---------------- fused setup: emb -> t_mod (redundant per block) -> ss slice; cvec ----
__global__ __launch_bounds__(256) void k_ssf(const void* tptr,
    const float* __restrict__ Wt1, const float* __restrict__ bt1,
    const float* __restrict__ Wt2, const float* __restrict__ bt2,
    const float* __restrict__ bb, const float* __restrict__ Wm1, const float* __restrict__ bm1,
    const float* __restrict__ Wa, const float* __restrict__ ba,
    float* __restrict__ ss_all, float* __restrict__ cvec)
{
    __shared__ float emb_s[256];
    __shared__ float part[2][128];
    __shared__ float tmp1_s[128];
    __shared__ float tmod_s[128];
    int tid = threadIdx.x;
    int iv = *(const int*)tptr;
    float fv = __int_as_float(iv);
    float tval = (iv > -1000000 && iv < 1000000) ? (float)iv : fv;
    {
        int fi = tid & 127;
        float fr = expf(-logf(10000.f) * (float)fi / 128.f);
        float ta = tval * fr;
        emb_s[tid] = (tid < 128) ? cosf(ta) : sinf(ta);
    }
    __syncthreads();
    {
        int col = tid & 127, sl = tid >> 7;
        float p = 0.f;
#pragma unroll 8
        for (int i = sl * 128; i < sl * 128 + 128; i++) p += emb_s[i] * Wt1[i * 128 + col];
        part[sl][col] = p;
    }
    __syncthreads();
    if (tid < 128) tmp1_s[tid] = silu_f(bt1[tid] + part[0][tid] + part[1][tid]);
    __syncthreads();
    {
        int col = tid & 127, sl = tid >> 7;
        float p = 0.f;
#pragma unroll 8
        for (int i = sl * 64; i < sl * 64 + 64; i++) p += tmp1_s[i] * Wt2[i * 128 + col];
        part[sl][col] = p;
    }
    __syncthreads();
    if (tid < 128) tmod_s[tid] = silu_f(bt2[tid] + part[0][tid] + part[1][tid]);
    __syncthreads();
    {
        int idx = blockIdx.x * 256 + tid;       // < 3072
        int l = idx >> 9, j = idx & 511;
        float a = ba[l * 512 + j];
        const float* w = Wa + l * 65536 + j;
#pragma unroll 4
        for (int k = 0; k < 128; k++) a += tmod_s[k] * w[k * 512];
        ss_all[idx] = a;
    }
    if (blockIdx.x == 0) {
        {
            int col = tid & 127, sl = tid >> 7;
            float p = 0.f;
#pragma unroll 8
            for (int i = sl * 64; i < sl * 64 + 64; i++) p += bb[i] * Wm1[i * 128 + col];
            part[sl][col] = p;
        }
        __syncthreads();
        if (tid < 128) cvec[tid] = bm1[tid] + part[0][tid] + part[1][tid];
    }
}

// ---------------- weight transpose+bf16: 196 tiles of 64x64 (incl. Wm1T) --------------
__global__ __launch_bounds__(256) void k_wtrans(
    const float* __restrict__ Wq, const float* __restrict__ Wk,
    const float* __restrict__ Wv, const float* __restrict__ Wsk,
    const float* __restrict__ Wf1, const float* __restrict__ Wf2,
    const float* __restrict__ Wm1, short* __restrict__ WT)
{
    __shared__ __align__(16) short T[64][80];
    int t = blockIdx.x;
    int tid = threadIdx.x;
    const float* src; short* dst; int K, N, kt, nt;
    if (t < 96) {
        int mat = t >> 2, sub = t & 3;
        int l = mat >> 2, m = mat & 3;
        src = (m == 0 ? Wq : m == 1 ? Wk : m == 2 ? Wv : Wsk) + l * 16384;
        dst = WT + (size_t)mat * 16384;
        K = 128; N = 128; kt = sub >> 1; nt = sub & 1;
    } else if (t < 144) {
        int i = t - 96; int l = i >> 3, sub = i & 7;
        src = Wf1 + l * 32768;
        dst = WT + 24 * 16384 + (size_t)l * 32768;
        K = 128; N = 256; kt = sub & 1; nt = sub >> 1;
    } else if (t < 192) {
        int i = t - 144; int l = i >> 3, sub = i & 7;
        src = Wf2 + l * 32768;
        dst = WT + 24 * 16384 + 6 * 32768 + (size_t)l * 32768;
        K = 256; N = 128; kt = sub >> 1; nt = sub & 1;
    } else {
        int sub = t - 192;
        src = Wm1;
        dst = WT + WM1T_OFF;
        K = 128; N = 128; kt = sub >> 1; nt = sub & 1;
    }
    int k0 = kt * 64, n0 = nt * 64;
    for (int p = 0; p < 16; p++) {
        int idx = p * 256 + tid;
        int kk = idx >> 6, nn = idx & 63;
        T[nn][kk] = (short)f2bf(src[(k0 + kk) * N + n0 + nn]);
    }
    __syncthreads();
    for (int p = 0; p < 2; p++) {
        int idx = p * 256 + tid;
        int nn = idx >> 3, sq = idx & 7;
        *(int4*)&dst[(size_t)(n0 + nn) * K + k0 + sq * 8] = *(const int4*)&T[nn][sq * 8];
    }
}

// ---------------- fused: h = x@Wn+bn (blocks 0..511) | edge_attr+deg (512..767) --------
__global__ __launch_bounds__(256) void k_inpedge(const float* __restrict__ x,
    const float* __restrict__ Wn, const float* __restrict__ bn, float* __restrict__ h,
    const int* __restrict__ ei, const float* __restrict__ tm,
    const float* __restrict__ Wee, const float* __restrict__ bee,
    float* __restrict__ ea, int* __restrict__ deg)
{
    int bid = blockIdx.x;
    int tid = threadIdx.x;
    if (bid < 512) {
        int idx = bid * 256 + tid;  // < 131072
        int i = idx >> 7, j = idx & 127;
        float acc = bn[j];
#pragma unroll
        for (int kk = 0; kk < 5; kk++) acc += x[i * 5 + kk] * Wn[kk * 128 + j];
        h[idx] = acc;
    } else {
        int e = (bid - 512) * 256 + tid;
        int s = ei[e], d = ei[EDGES + e];
        ea[e] = tm[s * N_NODES + d] * Wee[0] + bee[0];
        atomicAdd(&deg[d], 1);
    }
}

__global__ __launch_bounds__(1024) void k_scan(const int* __restrict__ deg, int* __restrict__ rowptr)
{
    __shared__ int tmp[1024];
    int tid = threadIdx.x;
    tmp[tid] = deg[tid];
    __syncthreads();
    for (int off = 1; off < 1024; off <<= 1) {
        int vv = (tid >= off) ? tmp[tid - off] : 0;
        __syncthreads();
        tmp[tid] += vv;
        __syncthreads();
    }
    rowptr[tid + 1] = tmp[tid];
    if (tid == 0) rowptr[0] = 0;
}

__global__ __launch_bounds__(256) void k_scatter(const int* __restrict__ ei,
    const int* __restrict__ rowptr, int* __restrict__ cursor, int* __restrict__ eorder)
{
    int e = blockIdx.x * 256 + threadIdx.x;
    int d = ei[EDGES + e];
    int pos = atomicAdd(&cursor[d], 1);
    eorder[rowptr[d] + pos] = e;
}

// ---------------- per-node bitonic sort + CSR flatten (fused) ----------------
__global__ __launch_bounds__(128) void k_sort2(const int* __restrict__ rowptr,
    int* __restrict__ eorder, const int* __restrict__ ei, const float* __restrict__ ea,
    int* __restrict__ src_csr, float* __restrict__ ea_csr)
{
    __shared__ int key[256];
    int node = blockIdx.x;
    int tid = threadIdx.x;
    int beg = rowptr[node], end = rowptr[node + 1];
    int n = end - beg;
    if (n <= 256) {
        for (int i = tid; i < 256; i += 128) key[i] = (i < n) ? eorder[beg + i] : 0x7FFFFFFF;
        __syncthreads();
        for (int k = 2; k <= 256; k <<= 1) {
            for (int j = k >> 1; j > 0; j >>= 1) {
                int i = ((tid / j) * 2 * j) + (tid % j);
                int l = i + j;
                bool up = ((i & k) == 0);
                int a = key[i], b = key[l];
                if ((a > b) == up) { key[i] = b; key[l] = a; }
                __syncthreads();
            }
        }
        for (int i = tid; i < n; i += 128) {
            int e = key[i];
            src_csr[beg + i] = ei[e];
            ea_csr[beg + i] = ea[e];
        }
    } else {
        if (tid == 0) {
            for (int i = beg + 1; i < end; ++i) {
                int kk = eorder[i];
                int j = i - 1;
                while (j >= beg && eorder[j] > kk) { eorder[j + 1] = eorder[j]; --j; }
                eorder[j + 1] = kk;
            }
        }
        __syncthreads();
        for (int i = tid; i < n; i += 128) {
            int e = eorder[beg + i];
            src_csr[beg + i] = ei[e];
            ea_csr[beg + i] = ea[e];
        }
    }
}

// ---------------- MFMA qkvs: 16 rows/block, wave-per-mat; k,v written bf16 ------------
__global__ __launch_bounds__(256) void k_qkvs(const float* __restrict__ h,
    const float* __restrict__ ss, const short* __restrict__ WT, int layer,
    const float* __restrict__ bq, const float* __restrict__ bk,
    const float* __restrict__ bv, const float* __restrict__ bsk,
    float* __restrict__ q, short* __restrict__ kb16, short* __restrict__ vb16,
    float* __restrict__ skp)
{
    __shared__ __align__(16) short As[16][136];
    __shared__ float shs[128], scs[128];
    int tid = threadIdx.x;
    int r0 = blockIdx.x * 16;
    if (tid < 128) { shs[tid] = ss[tid]; scs[tid] = ss[128 + tid]; }
    __syncthreads();
    {   // LN+mod: 16 threads per row, 8 cols each
        int row = tid >> 4, o = tid & 15;
        const float* hr = h + (size_t)(r0 + row) * 128 + o * 8;
        float s = 0.f, s2 = 0.f;
#pragma unroll
        for (int j = 0; j < 2; j++) {
            float4 vv = *(const float4*)&hr[j * 4];
            s += vv.x + vv.y + vv.z + vv.w;
            s2 += vv.x * vv.x + vv.y * vv.y + vv.z * vv.z + vv.w * vv.w;
        }
        s += __shfl_xor(s, 1, 64); s2 += __shfl_xor(s2, 1, 64);
        s += __shfl_xor(s, 2, 64); s2 += __shfl_xor(s2, 2, 64);
        s += __shfl_xor(s, 4, 64); s2 += __shfl_xor(s2, 4, 64);
        s += __shfl_xor(s, 8, 64); s2 += __shfl_xor(s2, 8, 64);
        float mu = s * (1.f / 128.f);
        float var = s2 * (1.f / 128.f) - mu * mu;
        float rs = rsqrtf(var + 1e-5f);
#pragma unroll
        for (int j = 0; j < 2; j++) {
            float4 vv = *(const float4*)&hr[j * 4];
            int cb = o * 8 + j * 4;
            short4 o4;
            o4.x = (short)f2bf((vv.x - mu) * rs * (1.f + scs[cb])     + shs[cb]);
            o4.y = (short)f2bf((vv.y - mu) * rs * (1.f + scs[cb + 1]) + shs[cb + 1]);
            o4.z = (short)f2bf((vv.z - mu) * rs * (1.f + scs[cb + 2]) + shs[cb + 2]);
            o4.w = (short)f2bf((vv.w - mu) * rs * (1.f + scs[cb + 3]) + shs[cb + 3]);
            *(short4*)&As[row][cb] = o4;
        }
    }
    __syncthreads();
    int w = tid >> 6, lane = tid & 63, c = lane & 15, g = lane >> 4;
    const short* Wm = WT + (size_t)(layer * 4 + w) * 16384;
    f32x4 acc[8] = {};
#pragma unroll
    for (int kq = 0; kq < 4; kq++) {
        int ko = kq * 32 + g * 8;
        bf16x8 a0 = *(const bf16x8*)&As[c][ko];
#pragma unroll
        for (int nt = 0; nt < 8; nt++) {
            bf16x8 bfr = *(const bf16x8*)&Wm[(size_t)(nt * 16 + c) * 128 + ko];
            acc[nt] = __builtin_amdgcn_mfma_f32_16x16x32_bf16(a0, bfr, acc[nt], 0, 0, 0);
        }
    }
    if (w == 0) {
#pragma unroll
        for (int nt = 0; nt < 8; nt++) {
            int n = nt * 16 + c;
            float bv2 = bq[n];
#pragma unroll
            for (int r = 0; r < 4; r++)
                q[(size_t)(r0 + g * 4 + r) * 128 + n] = acc[nt][r] + bv2;
        }
    } else if (w == 1) {
#pragma unroll
        for (int nt = 0; nt < 8; nt++) {
            int n = nt * 16 + c;
            float bv2 = bk[n];
#pragma unroll
            for (int r = 0; r < 4; r++)
                kb16[(size_t)(r0 + g * 4 + r) * 128 + n] = (short)f2bf(acc[nt][r] + bv2);
        }
    } else if (w == 2) {
#pragma unroll
        for (int nt = 0; nt < 8; nt++) {
            int n = nt * 16 + c;
            float bv2 = bv[n];
#pragma unroll
            for (int r = 0; r < 4; r++)
                vb16[(size_t)(r0 + g * 4 + r) * 128 + n] = (short)f2bf(acc[nt][r] + bv2);
        }
    } else {
#pragma unroll
        for (int nt = 0; nt < 8; nt++) {
            int n = nt * 16 + c;
            float bv2 = bsk[n];
#pragma unroll
            for (int r = 0; r < 4; r++)
                skp[(size_t)(r0 + g * 4 + r) * 128 + n] = acc[nt][r] + bv2;
        }
    }
}

// ---------------- MFMA FFN: 16 rows/block, grid 64; last layer also writes hb ---------
__global__ __launch_bounds__(256) void k_ffn(float* __restrict__ h,
    const short* __restrict__ WT, int layer,
    const float* __restrict__ bf1, const float* __restrict__ bf2,
    const float* __restrict__ ss2, short* __restrict__ hb, int last)
{
    __shared__ __align__(16) short As[16][136];
    __shared__ __align__(16) short Gs[16][264];
    __shared__ float shs[128], scs[128];
    int tid = threadIdx.x;
    int r0 = blockIdx.x * 16;
    if (tid < 128) { shs[tid] = ss2[tid]; scs[tid] = ss2[128 + tid]; }
    __syncthreads();
    {   // LN+mod
        int row = tid >> 4, o = tid & 15;
        const float* hr = h + (size_t)(r0 + row) * 128 + o * 8;
        float s = 0.f, s2 = 0.f;
#pragma unroll
        for (int j = 0; j < 2; j++) {
            float4 vv = *(const float4*)&hr[j * 4];
            s += vv.x + vv.y + vv.z + vv.w;
            s2 += vv.x * vv.x + vv.y * vv.y + vv.z * vv.z + vv.w * vv.w;
        }
        s += __shfl_xor(s, 1, 64); s2 += __shfl_xor(s2, 1, 64);
        s += __shfl_xor(s, 2, 64); s2 += __shfl_xor(s2, 2, 64);
        s += __shfl_xor(s, 4, 64); s2 += __shfl_xor(s2, 4, 64);
        s += __shfl_xor(s, 8, 64); s2 += __shfl_xor(s2, 8, 64);
        float mu = s * (1.f / 128.f);
        float var = s2 * (1.f / 128.f) - mu * mu;
        float rs = rsqrtf(var + 1e-5f);
#pragma unroll
        for (int j = 0; j < 2; j++) {
            float4 vv = *(const float4*)&hr[j * 4];
            int cb = o * 8 + j * 4;
            short4 o4;
            o4.x = (short)f2bf((vv.x - mu) * rs * (1.f + scs[cb])     + shs[cb]);
            o4.y = (short)f2bf((vv.y - mu) * rs * (1.f + scs[cb + 1]) + shs[cb + 1]);
            o4.z = (short)f2bf((vv.z - mu) * rs * (1.f + scs[cb + 2]) + shs[cb + 2]);
            o4.w = (short)f2bf((vv.w - mu) * rs * (1.f + scs[cb + 3]) + shs[cb + 3]);
            *(short4*)&As[row][cb] = o4;
        }
    }
    __syncthreads();
    int w = tid >> 6, lane = tid & 63, c = lane & 15, g = lane >> 4;
    const short* W1 = WT + 24 * 16384 + (size_t)layer * 32768;
    const short* W2 = WT + 24 * 16384 + 6 * 32768 + (size_t)layer * 32768;
    {   // f1
        f32x4 acc[4] = {};
#pragma unroll
        for (int kq = 0; kq < 4; kq++) {
            int ko = kq * 32 + g * 8;
            bf16x8 a0 = *(const bf16x8*)&As[c][ko];
#pragma unroll
            for (int nt = 0; nt < 4; nt++) {
                bf16x8 bfr = *(const bf16x8*)&W1[(size_t)(w * 64 + nt * 16 + c) * 128 + ko];
                acc[nt] = __builtin_amdgcn_mfma_f32_16x16x32_bf16(a0, bfr, acc[nt], 0, 0, 0);
            }
        }
#pragma unroll
        for (int nt = 0; nt < 4; nt++) {
            int n = w * 64 + nt * 16 + c;
            float bv = bf1[n];
#pragma unroll
            for (int r = 0; r < 4; r++) {
                float y = acc[nt][r] + bv;
                float gl = 0.5f * y * (1.f + erff(y * 0.70710678118654752f));
                Gs[g * 4 + r][n] = (short)f2bf(gl);
            }
        }
    }
    __syncthreads();
    {   // f2
        f32x4 acc2[2] = {};
#pragma unroll
        for (int kq = 0; kq < 8; kq++) {
            int ko = kq * 32 + g * 8;
            bf16x8 a0 = *(const bf16x8*)&Gs[c][ko];
#pragma unroll
            for (int nt2 = 0; nt2 < 2; nt2++) {
                bf16x8 bfr = *(const bf16x8*)&W2[(size_t)(w * 32 + nt2 * 16 + c) * 256 + ko];
                acc2[nt2] = __builtin_amdgcn_mfma_f32_16x16x32_bf16(a0, bfr, acc2[nt2], 0, 0, 0);
            }
        }
#pragma unroll
        for (int nt2 = 0; nt2 < 2; nt2++) {
            int n = w * 32 + nt2 * 16 + c;
            float bv = bf2[n];
#pragma unroll
            for (int r = 0; r < 4; r++) {
                int i = r0 + g * 4 + r;
                float nv = h[(size_t)i * 128 + n] + acc2[nt2][r] + bv;
                h[(size_t)i * 128 + n] = nv;
                if (last) hb[(size_t)i * 128 + n] = (short)f2bf(nv);
            }
        }
    }
}

// ---------------- attention: 4 waves per node, bf16 k/v gathers, LDS 4-way merge ------
__global__ __launch_bounds__(256) void k_attn(const float* __restrict__ q,
    const short* __restrict__ kb16, const short* __restrict__ vb16,
    const float* __restrict__ skp, float* __restrict__ h,
    const int* __restrict__ src_csr, const float* __restrict__ ea_csr,
    const float* __restrict__ We_l, const int* __restrict__ rowptr)
{
    __shared__ float ms[3][64], ssb[3][64], a0s[3][64], a1s[3][64];
    int tid = threadIdx.x;
    int wid = tid >> 6;            // 0..3 = quarter
    int lane = tid & 63;
    int node = blockIdx.x;
    int c0 = lane * 2;
    float2 q2 = *(const float2*)&q[node * 128 + c0];
    float we0 = We_l[c0], we1 = We_l[c0 + 1];
    int beg = rowptr[node], end = rowptr[node + 1];
    int n = end - beg;
    int tb = beg + (n * wid) / 4;
    int te = beg + (n * (wid + 1)) / 4;
    float m = -INFINITY, s = 0.f, a0 = 0.f, a1 = 0.f;
    const float isc = 0.17677669529663687f;  // 1/sqrt(32)

    int t = tb;
    for (; t + 3 < te; t += 4) {
        int sn0 = src_csr[t],     sn1 = src_csr[t + 1];
        int sn2 = src_csr[t + 2], sn3 = src_csr[t + 3];
        float e0 = ea_csr[t],     e1 = ea_csr[t + 1];
        float e2 = ea_csr[t + 2], e3 = ea_csr[t + 3];
        ushort2 ku0 = *(const ushort2*)&kb16[sn0 * 128 + c0];
        ushort2 ku1 = *(const ushort2*)&kb16[sn1 * 128 + c0];
        ushort2 ku2 = *(const ushort2*)&kb16[sn2 * 128 + c0];
        ushort2 ku3 = *(const ushort2*)&kb16[sn3 * 128 + c0];
        ushort2 vu0 = *(const ushort2*)&vb16[sn0 * 128 + c0];
        ushort2 vu1 = *(const ushort2*)&vb16[sn1 * 128 + c0];
        ushort2 vu2 = *(const ushort2*)&vb16[sn2 * 128 + c0];
        ushort2 vu3 = *(const ushort2*)&vb16[sn3 * 128 + c0];
        float p0 = q2.x * (bf2f(ku0.x) + e0 * we0) + q2.y * (bf2f(ku0.y) + e0 * we1);
        float p1 = q2.x * (bf2f(ku1.x) + e1 * we0) + q2.y * (bf2f(ku1.y) + e1 * we1);
        float p2 = q2.x * (bf2f(ku2.x) + e2 * we0) + q2.y * (bf2f(ku2.y) + e2 * we1);
        float p3 = q2.x * (bf2f(ku3.x) + e3 * we0) + q2.y * (bf2f(ku3.y) + e3 * we1);
        p0 += __shfl_xor(p0, 1, 16); p1 += __shfl_xor(p1, 1, 16);
        p2 += __shfl_xor(p2, 1, 16); p3 += __shfl_xor(p3, 1, 16);
        p0 += __shfl_xor(p0, 2, 16); p1 += __shfl_xor(p1, 2, 16);
        p2 += __shfl_xor(p2, 2, 16); p3 += __shfl_xor(p3, 2, 16);
        p0 += __shfl_xor(p0, 4, 16); p1 += __shfl_xor(p1, 4, 16);
        p2 += __shfl_xor(p2, 4, 16); p3 += __shfl_xor(p3, 4, 16);
        p0 += __shfl_xor(p0, 8, 16); p1 += __shfl_xor(p1, 8, 16);
        p2 += __shfl_xor(p2, 8, 16); p3 += __shfl_xor(p3, 8, 16);
        {
            float al = p0 * isc;
            float mn = fmaxf(m, al);
            float scale = __expf(m - mn), wq = __expf(al - mn);
            s = s * scale + wq;
            a0 = a0 * scale + wq * (bf2f(vu0.x) + e0 * we0);
            a1 = a1 * scale + wq * (bf2f(vu0.y) + e0 * we1);
            m = mn;
        }
        {
            float al = p1 * isc;
            float mn = fmaxf(m, al);
            float scale = __expf(m - mn), wq = __expf(al - mn);
            s = s * scale + wq;
            a0 = a0 * scale + wq * (bf2f(vu1.x) + e1 * we0);
            a1 = a1 * scale + wq * (bf2f(vu1.y) + e1 * we1);
            m = mn;
        }
        {
            float al = p2 * isc;
            float mn = fmaxf(m, al);
            float scale = __expf(m - mn), wq = __expf(al - mn);
            s = s * scale + wq;
            a0 = a0 * scale + wq * (bf2f(vu2.x) + e2 * we0);
            a1 = a1 * scale + wq * (bf2f(vu2.y) + e2 * we1);
            m = mn;
        }
        {
            float al = p3 * isc;
            float mn = fmaxf(m, al);
            float scale = __expf(m - mn), wq = __expf(al - mn);
            s = s * scale + wq;
            a0 = a0 * scale + wq * (bf2f(vu3.x) + e3 * we0);
            a1 = a1 * scale + wq * (bf2f(vu3.y) + e3 * we1);
            m = mn;
        }
    }
    for (; t < te; ++t) {
        int sn = src_csr[t];
        float eav = ea_csr[t];
        ushort2 ku = *(const ushort2*)&kb16[sn * 128 + c0];
        ushort2 vu = *(const ushort2*)&vb16[sn * 128 + c0];
        float part = q2.x * (bf2f(ku.x) + eav * we0) + q2.y * (bf2f(ku.y) + eav * we1);
        part += __shfl_xor(part, 1, 16);
        part += __shfl_xor(part, 2, 16);
        part += __shfl_xor(part, 4, 16);
        part += __shfl_xor(part, 8, 16);
        float alpha = part * isc;
        float mn = fmaxf(m, alpha);
        float scale = __expf(m - mn), wq = __expf(alpha - mn);
        s = s * scale + wq;
        a0 = a0 * scale + wq * (bf2f(vu.x) + eav * we0);
        a1 = a1 * scale + wq * (bf2f(vu.y) + eav * we1);
        m = mn;
    }
    if (wid > 0) {
        ms[wid - 1][lane] = m; ssb[wid - 1][lane] = s;
        a0s[wid - 1][lane] = a0; a1s[wid - 1][lane] = a1;
    }
    __syncthreads();
    if (wid == 0) {
#pragma unroll
        for (int p = 0; p < 3; p++) {
            float mB = ms[p][lane], sB = ssb[p][lane];
            float b0 = a0s[p][lane], b1 = a1s[p][lane];
            float mm = fmaxf(m, mB);
            float eA = (m  > -1e30f) ? __expf(m  - mm) : 0.f;
            float eB = (mB > -1e30f) ? __expf(mB - mm) : 0.f;
            s = s * eA + sB * eB;
            a0 = a0 * eA + b0 * eB;
            a1 = a1 * eA + b1 * eB;
            m = mm;
        }
        float inv = (s > 0.f) ? 1.f / (s + 1e-16f) : 0.f;
        int o = node * 128 + c0;
        h[o]     += skp[o]     + a0 * inv;
        h[o + 1] += skp[o + 1] + a1 * inv;
    }
}

// ---------------- MFMA mprep: per k, M_k[m][l] = Wm1T(m,o) x Wb_k(l,o)^T ----------------
__global__ __launch_bounds__(256) void k_mprep(const float* __restrict__ Wb,
    const short* __restrict__ WT, float* __restrict__ M)
{
    __shared__ __align__(16) short Bls[128][136];   // [l][o] bf16
    int tid = threadIdx.x;
    int k = blockIdx.x;
    const short* Wm1T = WT + WM1T_OFF;
    {
        int lq = (tid & 31) * 4;
        int ob = tid >> 5;  // 0..7
        for (int it = 0; it < 16; it++) {
            int o = it * 8 + ob;
            float4 vv = *(const float4*)&Wb[(size_t)o * 16384 + k * 128 + lq];
            Bls[lq][o]     = (short)f2bf(vv.x);
            Bls[lq + 1][o] = (short)f2bf(vv.y);
            Bls[lq + 2][o] = (short)f2bf(vv.z);
            Bls[lq + 3][o] = (short)f2bf(vv.w);
        }
    }
    __syncthreads();
    int w = tid >> 6, lane = tid & 63, c = lane & 15, g = lane >> 4;
    f32x4 acc[2][8] = {};
#pragma unroll
    for (int kq = 0; kq < 4; kq++) {
        int ko = kq * 32 + g * 8;
        bf16x8 a0 = *(const bf16x8*)&Wm1T[(size_t)(w * 32 + c) * 128 + ko];
        bf16x8 a1 = *(const bf16x8*)&Wm1T[(size_t)(w * 32 + 16 + c) * 128 + ko];
#pragma unroll
        for (int nt = 0; nt < 8; nt++) {
            bf16x8 b = *(const bf16x8*)&Bls[nt * 16 + c][ko];
            acc[0][nt] = __builtin_amdgcn_mfma_f32_16x16x32_bf16(a0, b, acc[0][nt], 0, 0, 0);
            acc[1][nt] = __builtin_amdgcn_mfma_f32_16x16x32_bf16(a1, b, acc[1][nt], 0, 0, 0);
        }
    }
    float* Mk = M + (size_t)k * 16384;
#pragma unroll
    for (int it = 0; it < 2; it++)
#pragma unroll
        for (int nt = 0; nt < 8; nt++)
#pragma unroll
            for (int r = 0; r < 4; r++) {
                int m = w * 32 + it * 16 + g * 4 + r;
                int l = nt * 16 + c;
                Mk[m * 128 + l] = acc[it][nt][r];
            }
}

// ---------------- Mt[n][k] (bf16) <- M[k][n] (fp32) ----------------
__global__ __launch_bounds__(256) void k_mtrans(const float* __restrict__ M,
                                                short* __restrict__ Mt)
{
    __shared__ __align__(16) short Ts[64][136];
    int tid = threadIdx.x;
    int n0 = blockIdx.x * 64;
    for (int p = 0; p < 32; p++) {
        int idx = p * 256 + tid;
        int k = idx >> 6, nn = idx & 63;
        Ts[nn][k] = (short)f2bf(M[(size_t)k * 16384 + n0 + nn]);
    }
    __syncthreads();
    for (int p = 0; p < 4; p++) {
        int idx = p * 256 + tid;
        int nn = idx >> 4, s = idx & 15;
        *(int4*)&Mt[(size_t)(n0 + nn) * 128 + s * 8] = *(const int4*)&Ts[nn][s * 8];
    }
}

// ---------------- phase1 MFMA: U[i][n] = sum_k hb[i,k] * Mt[n,k] ----------------
__global__ __launch_bounds__(256) void k_p1(const short* __restrict__ hb,
    const short* __restrict__ Mt, short* __restrict__ U)
{
    __shared__ __align__(16) short As[128][72];
    __shared__ __align__(16) short Bs[128][72];
    int tid = threadIdx.x;
    int n0 = blockIdx.x * 128;
    int i0 = blockIdx.y * 128;
    int w = tid >> 6, lane = tid & 63, c = lane & 15, g = lane >> 4;
    f32x4 acc[2][8] = {};
    for (int kh = 0; kh < 2; kh++) {
        __syncthreads();
        for (int idx = tid; idx < 1024; idx += 256) {
            int r = idx >> 3, s = idx & 7;
            *(int4*)&As[r][s * 8] = *(const int4*)&hb[(i0 + r) * 128 + kh * 64 + s * 8];
            *(int4*)&Bs[r][s * 8] = *(const int4*)&Mt[(size_t)(n0 + r) * 128 + kh * 64 + s * 8];
        }
        __syncthreads();
#pragma unroll
        for (int kk = 0; kk < 2; kk++) {
            int ko = kk * 32 + g * 8;
            bf16x8 a0 = *(const bf16x8*)&As[w * 32 + c][ko];
            bf16x8 a1 = *(const bf16x8*)&As[w * 32 + 16 + c][ko];
#pragma unroll
            for (int nt = 0; nt < 8; nt++) {
                bf16x8 b = *(const bf16x8*)&Bs[nt * 16 + c][ko];
                acc[0][nt] = __builtin_amdgcn_mfma_f32_16x16x32_bf16(a0, b, acc[0][nt], 0, 0, 0);
                acc[1][nt] = __builtin_amdgcn_mfma_f32_16x16x32_bf16(a1, b, acc[1][nt], 0, 0, 0);
            }
        }
    }
#pragma unroll
    for (int it = 0; it < 2; it++)
#pragma unroll
        for (int nt = 0; nt < 8; nt++)
#pragma unroll
            for (int r = 0; r < 4; r++) {
                int i = i0 + w * 32 + it * 16 + g * 4 + r;
                int n = n0 + nt * 16 + c;
                U[(size_t)i * 16384 + n] = (short)f2bf(acc[it][nt][r]);
            }
}

// ---------------- phase2 MFMA: (i, j-half) grid; XOR-swizzled Us; H frags from L2 ------
__global__ __launch_bounds__(256) void k_p2(const short* __restrict__ hb,
    const short* __restrict__ U, const float* __restrict__ cvec,
    const float* __restrict__ Wm2, const float* __restrict__ bm2,
    float* __restrict__ out)
{
    __shared__ __align__(16) short Us[128][128];   // row stride 256B, XOR swizzle
    __shared__ float cvs[128];
    __shared__ float w2s[128][4];
    int tid = threadIdx.x;
    int i = blockIdx.x;
    int jb = blockIdx.y;          // 0..1
    int b = i >> 8;
    int w = tid >> 6, lane = tid & 63, c = lane & 15, g = lane >> 4;
    if (tid < 128) {
        cvs[tid] = cvec[tid];
        *(float4*)&w2s[tid][0] = *(const float4*)&Wm2[tid * 4];
    }
    // preload the 8 H fragments this wave needs (hb is L2-resident)
    bf16x8 hf[2][4];
    {
        const short* hrow = hb + (size_t)(b * 256 + jb * 128 + w * 32 + c) * 128;
#pragma unroll
        for (int jt = 0; jt < 2; jt++)
#pragma unroll
            for (int kq = 0; kq < 4; kq++)
                hf[jt][kq] = *(const bf16x8*)(hrow + jt * 16 * 128 + kq * 32 + g * 8);
    }
    // stage U_i with XOR swizzle: slot s (8 shorts) -> s ^ (r&7)
    for (int idx = tid; idx < 2048; idx += 256) {
        int r = idx >> 4, s = idx & 15;
        int col = (s * 8) ^ ((r & 7) << 3);
        *(int4*)&Us[r][col] = *(const int4*)&U[(size_t)i * 16384 + r * 128 + s * 8];
    }
    __syncthreads();
    f32x4 acc[2][8] = {};
#pragma unroll
    for (int kq = 0; kq < 4; kq++) {
        int ko = kq * 32 + g * 8;
#pragma unroll
        for (int mt = 0; mt < 8; mt++) {
            int row = mt * 16 + c;
            int col = ko ^ ((row & 7) << 3);
            bf16x8 uv = *(const bf16x8*)&Us[row][col];
            acc[0][mt] = __builtin_amdgcn_mfma_f32_16x16x32_bf16(uv, hf[0][kq], acc[0][mt], 0, 0, 0);
            acc[1][mt] = __builtin_amdgcn_mfma_f32_16x16x32_bf16(uv, hf[1][kq], acc[1][mt], 0, 0, 0);
        }
    }
    float4 bmv = *(const float4*)&bm2[0];
#pragma unroll
    for (int jt = 0; jt < 2; jt++) {
        float p0 = 0.f, p1 = 0.f, p2 = 0.f, p3 = 0.f;
#pragma unroll
        for (int mt = 0; mt < 8; mt++) {
#pragma unroll
            for (int r = 0; r < 4; r++) {
                int m = mt * 16 + g * 4 + r;
                float y = acc[jt][mt][r] + cvs[m];
                float sv = y * frcp(1.f + __expf(-y));
                p0 += sv * w2s[m][0]; p1 += sv * w2s[m][1];
                p2 += sv * w2s[m][2]; p3 += sv * w2s[m][3];
            }
        }
        p0 += __shfl_xor(p0, 16, 64); p1 += __shfl_xor(p1, 16, 64);
        p2 += __shfl_xor(p2, 16, 64); p3 += __shfl_xor(p3, 16, 64);
        p0 += __shfl_xor(p0, 32, 64); p1 += __shfl_xor(p1, 32, 64);
        p2 += __shfl_xor(p2, 32, 64); p3 += __shfl_xor(p3, 32, 64);
        if (g == 0) {
            int j = jb * 128 + w * 32 + jt * 16 + c;
            float4 o4 = { p0 + bmv.x, p1 + bmv.y, p2 + bmv.z, p3 + bmv.w };
            *(float4*)&out[((size_t)i * 256 + j) * 4] = o4;
        }
    }
}

extern "C" void kernel_launch(void* const* d_in, const int* in_sizes, int n_in,
                              void* d_out, int out_size, void* d_ws, size_t ws_size,
                              hipStream_t stream)
{
    const float* x   = (const float*)d_in[0];
    const int*   ei  = (const int*)d_in[1];
    const void*  tptr= d_in[3];
    const float* tm  = (const float*)d_in[4];
    const float* Wn  = (const float*)d_in[5];
    const float* bn  = (const float*)d_in[6];
    const float* Wee = (const float*)d_in[7];
    const float* bee = (const float*)d_in[8];
    const float* Wt1 = (const float*)d_in[9];
    const float* bt1 = (const float*)d_in[10];
    const float* Wt2 = (const float*)d_in[11];
    const float* bt2 = (const float*)d_in[12];
    const float* Wa  = (const float*)d_in[13];
    const float* ba  = (const float*)d_in[14];
    const float* Wq  = (const float*)d_in[15];
    const float* bq  = (const float*)d_in[16];
    const float* Wk  = (const float*)d_in[17];
    const float* bk  = (const float*)d_in[18];
    const float* Wv  = (const float*)d_in[19];
    const float* bv  = (const float*)d_in[20];
    const float* We  = (const float*)d_in[21];
    const float* Wsk = (const float*)d_in[22];
    const float* bsk = (const float*)d_in[23];
    const float* Wf1 = (const float*)d_in[24];
    const float* bf1 = (const float*)d_in[25];
    const float* Wf2 = (const float*)d_in[26];
    const float* bf2 = (const float*)d_in[27];
    const float* Wb  = (const float*)d_in[28];
    const float* bb  = (const float*)d_in[29];
    const float* Wm1 = (const float*)d_in[30];
    const float* bm1 = (const float*)d_in[31];
    const float* Wm2 = (const float*)d_in[32];
    const float* bm2 = (const float*)d_in[33];
    float* out = (float*)d_out;
    float* ws = (float*)d_ws;

    float* h    = ws + OFF_H;
    float* qb   = ws + OFF_Q;
    short* kb16 = (short*)(ws + OFF_K);
    short* vb16 = (short*)(ws + OFF_V);
    float* skp  = ws + OFF_SKP;
    float* ss   = ws + OFF_SS;
    float* ea   = ws + OFF_EA;
    float* cvec = ws + OFF_CVEC;
    int* iws    = (int*)(ws + OFF_INT);
    int* deg    = iws;
    int* cursor = iws + 1024;
    int* rowptr = iws + 2048;
    int* eorder = iws + 3073;
    int* src_csr   = (int*)(ws + OFF_G);
    float* ea_csr  = ws + OFF_G + 65536;
    float* Mst  = ws + OFF_M;
    short* Ub   = (short*)(ws + OFF_U);
    short* Mtb  = (short*)(ws + OFF_MT);
    short* hbb  = (short*)(ws + OFF_HB);
    short* WT   = (short*)(ws + OFF_WB);

    hipMemsetAsync(deg, 0, 2048 * sizeof(int), stream);
    k_ssf<<<12, 256, 0, stream>>>(tptr, Wt1, bt1, Wt2, bt2, bb, Wm1, bm1, Wa, ba, ss, cvec);
    k_wtrans<<<196, 256, 0, stream>>>(Wq, Wk, Wv, Wsk, Wf1, Wf2, Wm1, WT);
    k_inpedge<<<768, 256, 0, stream>>>(x, Wn, bn, h, ei, tm, Wee, bee, ea, deg);
    k_scan<<<1, 1024, 0, stream>>>(deg, rowptr);
    k_scatter<<<256, 256, 0, stream>>>(ei, rowptr, cursor, eorder);
    k_sort2<<<1024, 128, 0, stream>>>(rowptr, eorder, ei, ea, src_csr, ea_csr);

    for (int l = 0; l < LAYERS; l++) {
        const float* ssl = ss + l * 512;
        k_qkvs<<<64, 256, 0, stream>>>(h, ssl, WT, l,
            bq + l * 128, bk + l * 128, bv + l * 128, bsk + l * 128,
            qb, kb16, vb16, skp);
        k_attn<<<1024, 256, 0, stream>>>(qb, kb16, vb16, skp, h, src_csr, ea_csr,
                                         We + l * 128, rowptr);
        k_ffn<<<64, 256, 0, stream>>>(h, WT, l, bf1 + l * 256, bf2 + l * 128,
                                      ssl + 256, hbb, l == LAYERS - 1);
    }

    k_mprep<<<128, 256, 0, stream>>>(Wb, WT, Mst);
    k_mtrans<<<256, 256, 0, stream>>>(Mst, Mtb);
    k_p1<<<dim3(128, 8), 256, 0, stream>>>(hbb, Mtb, Ub);
    k_p2<<<dim3(1024, 2), 256, 0, stream>>>(hbb, Ub, cvec, Wm2, bm2, out);
}

// Round 14
// 261.340 us; speedup vs baseline: 1.0571x; 1.0571x over previous
//
#include <hip/hip_runtime.h>
#include <math.h>

#define N_NODES 1024
#define HDIM 128
#define EDGES 65536
#define LAYERS 6

typedef __attribute__((ext_vector_type(8))) short bf16x8;
typedef __attribute__((ext_vector_type(4))) float f32x4;

// workspace float offsets
#define OFF_H     0
#define OFF_Q     131072
#define OFF_K     262144       // bf16 k [1024][128] (as short*)
#define OFF_V     393216       // bf16 v [1024][128] (as short*)
#define OFF_SKP   524288
#define OFF_G     655360       // src_csr (int E) + ea_csr (float E)
#define OFF_SS    917504
#define OFF_EA    920576
#define OFF_CVEC  986112
#define OFF_INT   986240
#define OFF_M     1054912      // fp32 M [128 k][16384 n], n = m*128 + l  (m-outer!)
#define OFF_U     3152064      // bf16 U [1024 i][16384 n]
#define OFF_MT    11540672     // bf16 Mt [16384 n][128 k]
#define OFF_HB    12589248     // bf16 hb [1024][128]
#define OFF_WB    12654912     // bf16 transposed weights + Wm1T

#define WM1T_OFF  786432       // short offset of Wm1T inside WT (kept for layout compat)

__device__ __forceinline__ float silu_f(float x) { return x / (1.f + expf(-x)); }
__device__ __forceinline__ float frcp(float x) { return __builtin_amdgcn_rcpf(x); }

__device__ __forceinline__ unsigned short f2bf(float f) {
    unsigned int u = __float_as_uint(f);
    u += 0x7FFFu + ((u >> 16) & 1u);
    return (unsigned short)(u >> 16);
}
__device__ __forceinline__ float bf2f(unsigned short s) {
    return __uint_as_float(((unsigned int)s) << 16);
}

// =====================================================================================
// mega setup: blocks 0..11 ssf | 12..207 wtrans | 208..975 inpedge | 976..1103 mprep
// =====================================================================================
__global__ __launch_bounds__(256) void k_setup_all(const void* tptr,
    const float* __restrict__ Wt1, const float* __restrict__ bt1,
    const float* __restrict__ Wt2, const float* __restrict__ bt2,
    const float* __restrict__ bb, const float* __restrict__ Wm1, const float* __restrict__ bm1,
    const float* __restrict__ Wa, const float* __restrict__ ba,
    float* __restrict__ ss_all, float* __restrict__ cvec,
    const float* __restrict__ Wq, const float* __restrict__ Wk,
    const float* __restrict__ Wv, const float* __restrict__ Wsk,
    const float* __restrict__ Wf1, const float* __restrict__ Wf2,
    short* __restrict__ WT,
    const float* __restrict__ x, const float* __restrict__ Wn, const float* __restrict__ bn,
    float* __restrict__ h, const int* __restrict__ ei, const float* __restrict__ tm,
    const float* __restrict__ Wee, const float* __restrict__ bee,
    float* __restrict__ ea, int* __restrict__ deg,
    const float* __restrict__ Wb, float* __restrict__ M)
{
    __shared__ __align__(16) char smem[69632];
    int bid = blockIdx.x;
    int tid = threadIdx.x;

    if (bid < 12) {
        // ---------------- ssf: emb -> t_mod (redundant) -> ss slice; cvec (block 0) ----
        float* emb_s  = (float*)smem;            // 256
        float* part   = emb_s + 256;             // 2*128
        float* tmp1_s = part + 256;              // 128
        float* tmod_s = tmp1_s + 128;            // 128
        int iv = *(const int*)tptr;
        float fv = __int_as_float(iv);
        float tval = (iv > -1000000 && iv < 1000000) ? (float)iv : fv;
        {
            int fi = tid & 127;
            float fr = expf(-logf(10000.f) * (float)fi / 128.f);
            float ta = tval * fr;
            emb_s[tid] = (tid < 128) ? cosf(ta) : sinf(ta);
        }
        __syncthreads();
        {
            int col = tid & 127, sl = tid >> 7;
            float p = 0.f;
#pragma unroll 8
            for (int i = sl * 128; i < sl * 128 + 128; i++) p += emb_s[i] * Wt1[i * 128 + col];
            part[sl * 128 + col] = p;
        }
        __syncthreads();
        if (tid < 128) tmp1_s[tid] = silu_f(bt1[tid] + part[tid] + part[128 + tid]);
        __syncthreads();
        {
            int col = tid & 127, sl = tid >> 7;
            float p = 0.f;
#pragma unroll 8
            for (int i = sl * 64; i < sl * 64 + 64; i++) p += tmp1_s[i] * Wt2[i * 128 + col];
            part[sl * 128 + col] = p;
        }
        __syncthreads();
        if (tid < 128) tmod_s[tid] = silu_f(bt2[tid] + part[tid] + part[128 + tid]);
        __syncthreads();
        {
            int idx = bid * 256 + tid;       // < 3072
            int l = idx >> 9, j = idx & 511;
            float a = ba[l * 512 + j];
            const float* w = Wa + l * 65536 + j;
#pragma unroll 4
            for (int k = 0; k < 128; k++) a += tmod_s[k] * w[k * 512];
            ss_all[idx] = a;
        }
        if (bid == 0) {
            {
                int col = tid & 127, sl = tid >> 7;
                float p = 0.f;
#pragma unroll 8
                for (int i = sl * 64; i < sl * 64 + 64; i++) p += bb[i] * Wm1[i * 128 + col];
                part[sl * 128 + col] = p;
            }
            __syncthreads();
            if (tid < 128) cvec[tid] = bm1[tid] + part[tid] + part[128 + tid];
        }
    } else if (bid < 208) {
        // ---------------- wtrans: 196 tiles of 64x64 (incl. Wm1T for compat) ----------
        short (*T)[80] = (short(*)[80])smem;
        int t = bid - 12;
        const float* src; short* dst; int K, N, kt, nt;
        if (t < 96) {
            int mat = t >> 2, sub = t & 3;
            int l = mat >> 2, m = mat & 3;
            src = (m == 0 ? Wq : m == 1 ? Wk : m == 2 ? Wv : Wsk) + l * 16384;
            dst = WT + (size_t)mat * 16384;
            K = 128; N = 128; kt = sub >> 1; nt = sub & 1;
        } else if (t < 144) {
            int i = t - 96; int l = i >> 3, sub = i & 7;
            src = Wf1 + l * 32768;
            dst = WT + 24 * 16384 + (size_t)l * 32768;
            K = 128; N = 256; kt = sub & 1; nt = sub >> 1;
        } else if (t < 192) {
            int i = t - 144; int l = i >> 3, sub = i & 7;
            src = Wf2 + l * 32768;
            dst = WT + 24 * 16384 + 6 * 32768 + (size_t)l * 32768;
            K = 256; N = 128; kt = sub >> 1; nt = sub & 1;
        } else {
            int sub = t - 192;
            src = Wm1;
            dst = WT + WM1T_OFF;
            K = 128; N = 128; kt = sub >> 1; nt = sub & 1;
        }
        int k0 = kt * 64, n0 = nt * 64;
        for (int p = 0; p < 16; p++) {
            int idx = p * 256 + tid;
            int kk = idx >> 6, nn = idx & 63;
            T[nn][kk] = (short)f2bf(src[(k0 + kk) * N + n0 + nn]);
        }
        __syncthreads();
        for (int p = 0; p < 2; p++) {
            int idx = p * 256 + tid;
            int nn = idx >> 3, sq = idx & 7;
            *(int4*)&dst[(size_t)(n0 + nn) * K + k0 + sq * 8] = *(const int4*)&T[nn][sq * 8];
        }
    } else if (bid < 976) {
        // ---------------- inpedge ----------------
        int b2 = bid - 208;
        if (b2 < 512) {
            int idx = b2 * 256 + tid;  // < 131072
            int i = idx >> 7, j = idx & 127;
            float acc = bn[j];
#pragma unroll
            for (int kk = 0; kk < 5; kk++) acc += x[i * 5 + kk] * Wn[kk * 128 + j];
            h[idx] = acc;
        } else {
            int e = (b2 - 512) * 256 + tid;
            int s = ei[e], d = ei[EDGES + e];
            ea[e] = tm[s * N_NODES + d] * Wee[0] + bee[0];
            atomicAdd(&deg[d], 1);
        }
    } else {
        // ---------------- mprep (MFMA): M_k[m][l] = sum_o Wm1[o][m] * Wb[o,k,l] -------
        short (*Bls)[136]   = (short(*)[136])smem;            // [l][o]
        short (*Wm1Tl)[136] = (short(*)[136])(smem + 34816);  // [m][o]
        int k = bid - 976;
        {   // stage Wb[:,k,:] transposed
            int lq = (tid & 31) * 4;
            int ob = tid >> 5;  // 0..7
            for (int it = 0; it < 16; it++) {
                int o = it * 8 + ob;
                float4 vv = *(const float4*)&Wb[(size_t)o * 16384 + k * 128 + lq];
                Bls[lq][o]     = (short)f2bf(vv.x);
                Bls[lq + 1][o] = (short)f2bf(vv.y);
                Bls[lq + 2][o] = (short)f2bf(vv.z);
                Bls[lq + 3][o] = (short)f2bf(vv.w);
            }
        }
        {   // stage Wm1 transposed: Wm1Tl[m][o] <- Wm1[o][m]
            int m = tid & 127;
            int oh = tid >> 7;   // 0..1
            for (int it = 0; it < 64; it++) {
                int o = it * 2 + oh;
                Wm1Tl[m][o] = (short)f2bf(Wm1[o * 128 + m]);
            }
        }
        __syncthreads();
        int w = tid >> 6, lane = tid & 63, c = lane & 15, g = lane >> 4;
        f32x4 acc[2][8] = {};
#pragma unroll
        for (int kq = 0; kq < 4; kq++) {
            int ko = kq * 32 + g * 8;
            bf16x8 a0 = *(const bf16x8*)&Wm1Tl[w * 32 + c][ko];
            bf16x8 a1 = *(const bf16x8*)&Wm1Tl[w * 32 + 16 + c][ko];
#pragma unroll
            for (int nt = 0; nt < 8; nt++) {
                bf16x8 b = *(const bf16x8*)&Bls[nt * 16 + c][ko];
                acc[0][nt] = __builtin_amdgcn_mfma_f32_16x16x32_bf16(a0, b, acc[0][nt], 0, 0, 0);
                acc[1][nt] = __builtin_amdgcn_mfma_f32_16x16x32_bf16(a1, b, acc[1][nt], 0, 0, 0);
            }
        }
        float* Mk = M + (size_t)k * 16384;
#pragma unroll
        for (int it = 0; it < 2; it++)
#pragma unroll
            for (int nt = 0; nt < 8; nt++)
#pragma unroll
                for (int r = 0; r < 4; r++) {
                    int m = w * 32 + it * 16 + g * 4 + r;
                    int l = nt * 16 + c;
                    Mk[m * 128 + l] = acc[it][nt][r];
                }
    }
}

__global__ __launch_bounds__(1024) void k_scan(const int* __restrict__ deg, int* __restrict__ rowptr)
{
    __shared__ int tmp[1024];
    int tid = threadIdx.x;
    tmp[tid] = deg[tid];
    __syncthreads();
    for (int off = 1; off < 1024; off <<= 1) {
        int vv = (tid >= off) ? tmp[tid - off] : 0;
        __syncthreads();
        tmp[tid] += vv;
        __syncthreads();
    }
    rowptr[tid + 1] = tmp[tid];
    if (tid == 0) rowptr[0] = 0;
}

__global__ __launch_bounds__(256) void k_scatter(const int* __restrict__ ei,
    const int* __restrict__ rowptr, int* __restrict__ cursor, int* __restrict__ eorder)
{
    int e = blockIdx.x * 256 + threadIdx.x;
    int d = ei[EDGES + e];
    int pos = atomicAdd(&cursor[d], 1);
    eorder[rowptr[d] + pos] = e;
}

// ---------------- per-node bitonic sort + CSR flatten (fused) ----------------
__global__ __launch_bounds__(128) void k_sort2(const int* __restrict__ rowptr,
    int* __restrict__ eorder, const int* __restrict__ ei, const float* __restrict__ ea,
    int* __restrict__ src_csr, float* __restrict__ ea_csr)
{
    __shared__ int key[256];
    int node = blockIdx.x;
    int tid = threadIdx.x;
    int beg = rowptr[node], end = rowptr[node + 1];
    int n = end - beg;
    if (n <= 256) {
        for (int i = tid; i < 256; i += 128) key[i] = (i < n) ? eorder[beg + i] : 0x7FFFFFFF;
        __syncthreads();
        for (int k = 2; k <= 256; k <<= 1) {
            for (int j = k >> 1; j > 0; j >>= 1) {
                int i = ((tid / j) * 2 * j) + (tid % j);
                int l = i + j;
                bool up = ((i & k) == 0);
                int a = key[i], b = key[l];
                if ((a > b) == up) { key[i] = b; key[l] = a; }
                __syncthreads();
            }
        }
        for (int i = tid; i < n; i += 128) {
            int e = key[i];
            src_csr[beg + i] = ei[e];
            ea_csr[beg + i] = ea[e];
        }
    } else {
        if (tid == 0) {
            for (int i = beg + 1; i < end; ++i) {
                int kk = eorder[i];
                int j = i - 1;
                while (j >= beg && eorder[j] > kk) { eorder[j + 1] = eorder[j]; --j; }
                eorder[j + 1] = kk;
            }
        }
        __syncthreads();
        for (int i = tid; i < n; i += 128) {
            int e = eorder[beg + i];
            src_csr[beg + i] = ei[e];
            ea_csr[beg + i] = ea[e];
        }
    }
}

// ---------------- MFMA qkvs: 16 rows/block, wave-per-mat; k,v written bf16 ------------
__global__ __launch_bounds__(256) void k_qkvs(const float* __restrict__ h,
    const float* __restrict__ ss, const short* __restrict__ WT, int layer,
    const float* __restrict__ bq, const float* __restrict__ bk,
    const float* __restrict__ bv, const float* __restrict__ bsk,
    float* __restrict__ q, short* __restrict__ kb16, short* __restrict__ vb16,
    float* __restrict__ skp)
{
    __shared__ __align__(16) short As[16][136];
    __shared__ float shs[128], scs[128];
    int tid = threadIdx.x;
    int r0 = blockIdx.x * 16;
    if (tid < 128) { shs[tid] = ss[tid]; scs[tid] = ss[128 + tid]; }
    __syncthreads();
    {   // LN+mod: 16 threads per row, 8 cols each
        int row = tid >> 4, o = tid & 15;
        const float* hr = h + (size_t)(r0 + row) * 128 + o * 8;
        float s = 0.f, s2 = 0.f;
#pragma unroll
        for (int j = 0; j < 2; j++) {
            float4 vv = *(const float4*)&hr[j * 4];
            s += vv.x + vv.y + vv.z + vv.w;
            s2 += vv.x * vv.x + vv.y * vv.y + vv.z * vv.z + vv.w * vv.w;
        }
        s += __shfl_xor(s, 1, 64); s2 += __shfl_xor(s2, 1, 64);
        s += __shfl_xor(s, 2, 64); s2 += __shfl_xor(s2, 2, 64);
        s += __shfl_xor(s, 4, 64); s2 += __shfl_xor(s2, 4, 64);
        s += __shfl_xor(s, 8, 64); s2 += __shfl_xor(s2, 8, 64);
        float mu = s * (1.f / 128.f);
        float var = s2 * (1.f / 128.f) - mu * mu;
        float rs = rsqrtf(var + 1e-5f);
#pragma unroll
        for (int j = 0; j < 2; j++) {
            float4 vv = *(const float4*)&hr[j * 4];
            int cb = o * 8 + j * 4;
            short4 o4;
            o4.x = (short)f2bf((vv.x - mu) * rs * (1.f + scs[cb])     + shs[cb]);
            o4.y = (short)f2bf((vv.y - mu) * rs * (1.f + scs[cb + 1]) + shs[cb + 1]);
            o4.z = (short)f2bf((vv.z - mu) * rs * (1.f + scs[cb + 2]) + shs[cb + 2]);
            o4.w = (short)f2bf((vv.w - mu) * rs * (1.f + scs[cb + 3]) + shs[cb + 3]);
            *(short4*)&As[row][cb] = o4;
        }
    }
    __syncthreads();
    int w = tid >> 6, lane = tid & 63, c = lane & 15, g = lane >> 4;
    const short* Wm = WT + (size_t)(layer * 4 + w) * 16384;
    f32x4 acc[8] = {};
#pragma unroll
    for (int kq = 0; kq < 4; kq++) {
        int ko = kq * 32 + g * 8;
        bf16x8 a0 = *(const bf16x8*)&As[c][ko];
#pragma unroll
        for (int nt = 0; nt < 8; nt++) {
            bf16x8 bfr = *(const bf16x8*)&Wm[(size_t)(nt * 16 + c) * 128 + ko];
            acc[nt] = __builtin_amdgcn_mfma_f32_16x16x32_bf16(a0, bfr, acc[nt], 0, 0, 0);
        }
    }
    if (w == 0) {
#pragma unroll
        for (int nt = 0; nt < 8; nt++) {
            int n = nt * 16 + c;
            float bv2 = bq[n];
#pragma unroll
            for (int r = 0; r < 4; r++)
                q[(size_t)(r0 + g * 4 + r) * 128 + n] = acc[nt][r] + bv2;
        }
    } else if (w == 1) {
#pragma unroll
        for (int nt = 0; nt < 8; nt++) {
            int n = nt * 16 + c;
            float bv2 = bk[n];
#pragma unroll
            for (int r = 0; r < 4; r++)
                kb16[(size_t)(r0 + g * 4 + r) * 128 + n] = (short)f2bf(acc[nt][r] + bv2);
        }
    } else if (w == 2) {
#pragma unroll
        for (int nt = 0; nt < 8; nt++) {
            int n = nt * 16 + c;
            float bv2 = bv[n];
#pragma unroll
            for (int r = 0; r < 4; r++)
                vb16[(size_t)(r0 + g * 4 + r) * 128 + n] = (short)f2bf(acc[nt][r] + bv2);
        }
    } else {
#pragma unroll
        for (int nt = 0; nt < 8; nt++) {
            int n = nt * 16 + c;
            float bv2 = bsk[n];
#pragma unroll
            for (int r = 0; r < 4; r++)
                skp[(size_t)(r0 + g * 4 + r) * 128 + n] = acc[nt][r] + bv2;
        }
    }
}

// ---------------- MFMA FFN: 16 rows/block, grid 64; last layer also writes hb ---------
__global__ __launch_bounds__(256) void k_ffn(float* __restrict__ h,
    const short* __restrict__ WT, int layer,
    const float* __restrict__ bf1, const float* __restrict__ bf2,
    const float* __restrict__ ss2, short* __restrict__ hb, int last)
{
    __shared__ __align__(16) short As[16][136];
    __shared__ __align__(16) short Gs[16][264];
    __shared__ float shs[128], scs[128];
    int tid = threadIdx.x;
    int r0 = blockIdx.x * 16;
    if (tid < 128) { shs[tid] = ss2[tid]; scs[tid] = ss2[128 + tid]; }
    __syncthreads();
    {   // LN+mod
        int row = tid >> 4, o = tid & 15;
        const float* hr = h + (size_t)(r0 + row) * 128 + o * 8;
        float s = 0.f, s2 = 0.f;
#pragma unroll
        for (int j = 0; j < 2; j++) {
            float4 vv = *(const float4*)&hr[j * 4];
            s += vv.x + vv.y + vv.z + vv.w;
            s2 += vv.x * vv.x + vv.y * vv.y + vv.z * vv.z + vv.w * vv.w;
        }
        s += __shfl_xor(s, 1, 64); s2 += __shfl_xor(s2, 1, 64);
        s += __shfl_xor(s, 2, 64); s2 += __shfl_xor(s2, 2, 64);
        s += __shfl_xor(s, 4, 64); s2 += __shfl_xor(s2, 4, 64);
        s += __shfl_xor(s, 8, 64); s2 += __shfl_xor(s2, 8, 64);
        float mu = s * (1.f / 128.f);
        float var = s2 * (1.f / 128.f) - mu * mu;
        float rs = rsqrtf(var + 1e-5f);
#pragma unroll
        for (int j = 0; j < 2; j++) {
            float4 vv = *(const float4*)&hr[j * 4];
            int cb = o * 8 + j * 4;
            short4 o4;
            o4.x = (short)f2bf((vv.x - mu) * rs * (1.f + scs[cb])     + shs[cb]);
            o4.y = (short)f2bf((vv.y - mu) * rs * (1.f + scs[cb + 1]) + shs[cb + 1]);
            o4.z = (short)f2bf((vv.z - mu) * rs * (1.f + scs[cb + 2]) + shs[cb + 2]);
            o4.w = (short)f2bf((vv.w - mu) * rs * (1.f + scs[cb + 3]) + shs[cb + 3]);
            *(short4*)&As[row][cb] = o4;
        }
    }
    __syncthreads();
    int w = tid >> 6, lane = tid & 63, c = lane & 15, g = lane >> 4;
    const short* W1 = WT + 24 * 16384 + (size_t)layer * 32768;
    const short* W2 = WT + 24 * 16384 + 6 * 32768 + (size_t)layer * 32768;
    {   // f1
        f32x4 acc[4] = {};
#pragma unroll
        for (int kq = 0; kq < 4; kq++) {
            int ko = kq * 32 + g * 8;
            bf16x8 a0 = *(const bf16x8*)&As[c][ko];
#pragma unroll
            for (int nt = 0; nt < 4; nt++) {
                bf16x8 bfr = *(const bf16x8*)&W1[(size_t)(w * 64 + nt * 16 + c) * 128 + ko];
                acc[nt] = __builtin_amdgcn_mfma_f32_16x16x32_bf16(a0, bfr, acc[nt], 0, 0, 0);
            }
        }
#pragma unroll
        for (int nt = 0; nt < 4; nt++) {
            int n = w * 64 + nt * 16 + c;
            float bv = bf1[n];
#pragma unroll
            for (int r = 0; r < 4; r++) {
                float y = acc[nt][r] + bv;
                float gl = 0.5f * y * (1.f + erff(y * 0.70710678118654752f));
                Gs[g * 4 + r][n] = (short)f2bf(gl);
            }
        }
    }
    __syncthreads();
    {   // f2
        f32x4 acc2[2] = {};
#pragma unroll
        for (int kq = 0; kq < 8; kq++) {
            int ko = kq * 32 + g * 8;
            bf16x8 a0 = *(const bf16x8*)&Gs[c][ko];
#pragma unroll
            for (int nt2 = 0; nt2 < 2; nt2++) {
                bf16x8 bfr = *(const bf16x8*)&W2[(size_t)(w * 32 + nt2 * 16 + c) * 256 + ko];
                acc2[nt2] = __builtin_amdgcn_mfma_f32_16x16x32_bf16(a0, bfr, acc2[nt2], 0, 0, 0);
            }
        }
#pragma unroll
        for (int nt2 = 0; nt2 < 2; nt2++) {
            int n = w * 32 + nt2 * 16 + c;
            float bv = bf2[n];
#pragma unroll
            for (int r = 0; r < 4; r++) {
                int i = r0 + g * 4 + r;
                float nv = h[(size_t)i * 128 + n] + acc2[nt2][r] + bv;
                h[(size_t)i * 128 + n] = nv;
                if (last) hb[(size_t)i * 128 + n] = (short)f2bf(nv);
            }
        }
    }
}

// ---------------- attention: 4 waves per node, bf16 k/v gathers, LDS 4-way merge ------
__global__ __launch_bounds__(256) void k_attn(const float* __restrict__ q,
    const short* __restrict__ kb16, const short* __restrict__ vb16,
    const float* __restrict__ skp, float* __restrict__ h,
    const int* __restrict__ src_csr, const float* __restrict__ ea_csr,
    const float* __restrict__ We_l, const int* __restrict__ rowptr)
{
    __shared__ float ms[3][64], ssb[3][64], a0s[3][64], a1s[3][64];
    int tid = threadIdx.x;
    int wid = tid >> 6;            // 0..3 = quarter
    int lane = tid & 63;
    int node = blockIdx.x;
    int c0 = lane * 2;
    float2 q2 = *(const float2*)&q[node * 128 + c0];
    float we0 = We_l[c0], we1 = We_l[c0 + 1];
    int beg = rowptr[node], end = rowptr[node + 1];
    int n = end - beg;
    int tb = beg + (n * wid) / 4;
    int te = beg + (n * (wid + 1)) / 4;
    float m = -INFINITY, s = 0.f, a0 = 0.f, a1 = 0.f;
    const float isc = 0.17677669529663687f;  // 1/sqrt(32)

    int t = tb;
    for (; t + 3 < te; t += 4) {
        int sn0 = src_csr[t],     sn1 = src_csr[t + 1];
        int sn2 = src_csr[t + 2], sn3 = src_csr[t + 3];
        float e0 = ea_csr[t],     e1 = ea_csr[t + 1];
        float e2 = ea_csr[t + 2], e3 = ea_csr[t + 3];
        ushort2 ku0 = *(const ushort2*)&kb16[sn0 * 128 + c0];
        ushort2 ku1 = *(const ushort2*)&kb16[sn1 * 128 + c0];
        ushort2 ku2 = *(const ushort2*)&kb16[sn2 * 128 + c0];
        ushort2 ku3 = *(const ushort2*)&kb16[sn3 * 128 + c0];
        ushort2 vu0 = *(const ushort2*)&vb16[sn0 * 128 + c0];
        ushort2 vu1 = *(const ushort2*)&vb16[sn1 * 128 + c0];
        ushort2 vu2 = *(const ushort2*)&vb16[sn2 * 128 + c0];
        ushort2 vu3 = *(const ushort2*)&vb16[sn3 * 128 + c0];
        float p0 = q2.x * (bf2f(ku0.x) + e0 * we0) + q2.y * (bf2f(ku0.y) + e0 * we1);
        float p1 = q2.x * (bf2f(ku1.x) + e1 * we0) + q2.y * (bf2f(ku1.y) + e1 * we1);
        float p2 = q2.x * (bf2f(ku2.x) + e2 * we0) + q2.y * (bf2f(ku2.y) + e2 * we1);
        float p3 = q2.x * (bf2f(ku3.x) + e3 * we0) + q2.y * (bf2f(ku3.y) + e3 * we1);
        p0 += __shfl_xor(p0, 1, 16); p1 += __shfl_xor(p1, 1, 16);
        p2 += __shfl_xor(p2, 1, 16); p3 += __shfl_xor(p3, 1, 16);
        p0 += __shfl_xor(p0, 2, 16); p1 += __shfl_xor(p1, 2, 16);
        p2 += __shfl_xor(p2, 2, 16); p3 += __shfl_xor(p3, 2, 16);
        p0 += __shfl_xor(p0, 4, 16); p1 += __shfl_xor(p1, 4, 16);
        p2 += __shfl_xor(p2, 4, 16); p3 += __shfl_xor(p3, 4, 16);
        p0 += __shfl_xor(p0, 8, 16); p1 += __shfl_xor(p1, 8, 16);
        p2 += __shfl_xor(p2, 8, 16); p3 += __shfl_xor(p3, 8, 16);
        {
            float al = p0 * isc;
            float mn = fmaxf(m, al);
            float scale = __expf(m - mn), wq = __expf(al - mn);
            s = s * scale + wq;
            a0 = a0 * scale + wq * (bf2f(vu0.x) + e0 * we0);
            a1 = a1 * scale + wq * (bf2f(vu0.y) + e0 * we1);
            m = mn;
        }
        {
            float al = p1 * isc;
            float mn = fmaxf(m, al);
            float scale = __expf(m - mn), wq = __expf(al - mn);
            s = s * scale + wq;
            a0 = a0 * scale + wq * (bf2f(vu1.x) + e1 * we0);
            a1 = a1 * scale + wq * (bf2f(vu1.y) + e1 * we1);
            m = mn;
        }
        {
            float al = p2 * isc;
            float mn = fmaxf(m, al);
            float scale = __expf(m - mn), wq = __expf(al - mn);
            s = s * scale + wq;
            a0 = a0 * scale + wq * (bf2f(vu2.x) + e2 * we0);
            a1 = a1 * scale + wq * (bf2f(vu2.y) + e2 * we1);
            m = mn;
        }
        {
            float al = p3 * isc;
            float mn = fmaxf(m, al);
            float scale = __expf(m - mn), wq = __expf(al - mn);
            s = s * scale + wq;
            a0 = a0 * scale + wq * (bf2f(vu3.x) + e3 * we0);
            a1 = a1 * scale + wq * (bf2f(vu3.y) + e3 * we1);
            m = mn;
        }
    }
    for (; t < te; ++t) {
        int sn = src_csr[t];
        float eav = ea_csr[t];
        ushort2 ku = *(const ushort2*)&kb16[sn * 128 + c0];
        ushort2 vu = *(const ushort2*)&vb16[sn * 128 + c0];
        float part = q2.x * (bf2f(ku.x) + eav * we0) + q2.y * (bf2f(ku.y) + eav * we1);
        part += __shfl_xor(part, 1, 16);
        part += __shfl_xor(part, 2, 16);
        part += __shfl_xor(part, 4, 16);
        part += __shfl_xor(part, 8, 16);
        float alpha = part * isc;
        float mn = fmaxf(m, alpha);
        float scale = __expf(m - mn), wq = __expf(alpha - mn);
        s = s * scale + wq;
        a0 = a0 * scale + wq * (bf2f(vu.x) + eav * we0);
        a1 = a1 * scale + wq * (bf2f(vu.y) + eav * we1);
        m = mn;
    }
    if (wid > 0) {
        ms[wid - 1][lane] = m; ssb[wid - 1][lane] = s;
        a0s[wid - 1][lane] = a0; a1s[wid - 1][lane] = a1;
    }
    __syncthreads();
    if (wid == 0) {
#pragma unroll
        for (int p = 0; p < 3; p++) {
            float mB = ms[p][lane], sB = ssb[p][lane];
            float b0 = a0s[p][lane], b1 = a1s[p][lane];
            float mm = fmaxf(m, mB);
            float eA = (m  > -1e30f) ? __expf(m  - mm) : 0.f;
            float eB = (mB > -1e30f) ? __expf(mB - mm) : 0.f;
            s = s * eA + sB * eB;
            a0 = a0 * eA + b0 * eB;
            a1 = a1 * eA + b1 * eB;
            m = mm;
        }
        float inv = (s > 0.f) ? 1.f / (s + 1e-16f) : 0.f;
        int o = node * 128 + c0;
        h[o]     += skp[o]     + a0 * inv;
        h[o + 1] += skp[o + 1] + a1 * inv;
    }
}

// ---------------- Mt[n][k] (bf16) <- M[k][n] (fp32) ----------------
__global__ __launch_bounds__(256) void k_mtrans(const float* __restrict__ M,
                                                short* __restrict__ Mt)
{
    __shared__ __align__(16) short Ts[64][136];
    int tid = threadIdx.x;
    int n0 = blockIdx.x * 64;
    for (int p = 0; p < 32; p++) {
        int idx = p * 256 + tid;
        int k = idx >> 6, nn = idx & 63;
        Ts[nn][k] = (short)f2bf(M[(size_t)k * 16384 + n0 + nn]);
    }
    __syncthreads();
    for (int p = 0; p < 4; p++) {
        int idx = p * 256 + tid;
        int nn = idx >> 4, s = idx & 15;
        *(int4*)&Mt[(size_t)(n0 + nn) * 128 + s * 8] = *(const int4*)&Ts[nn][s * 8];
    }
}

// ---------------- phase1 MFMA: grid (8 i-tiles, 128 n-tiles) for Mt L3 reuse ----------
__global__ __launch_bounds__(256) void k_p1(const short* __restrict__ hb,
    const short* __restrict__ Mt, short* __restrict__ U)
{
    __shared__ __align__(16) short As[128][72];
    __shared__ __align__(16) short Bs[128][72];
    int tid = threadIdx.x;
    int i0 = blockIdx.x * 128;
    int n0 = blockIdx.y * 128;
    int w = tid >> 6, lane = tid & 63, c = lane & 15, g = lane >> 4;
    f32x4 acc[2][8] = {};
    for (int kh = 0; kh < 2; kh++) {
        __syncthreads();
        for (int idx = tid; idx < 1024; idx += 256) {
            int r = idx >> 3, s = idx & 7;
            *(int4*)&As[r][s * 8] = *(const int4*)&hb[(i0 + r) * 128 + kh * 64 + s * 8];
            *(int4*)&Bs[r][s * 8] = *(const int4*)&Mt[(size_t)(n0 + r) * 128 + kh * 64 + s * 8];
        }
        __syncthreads();
#pragma unroll
        for (int kk = 0; kk < 2; kk++) {
            int ko = kk * 32 + g * 8;
            bf16x8 a0 = *(const bf16x8*)&As[w * 32 + c][ko];
            bf16x8 a1 = *(const bf16x8*)&As[w * 32 + 16 + c][ko];
#pragma unroll
            for (int nt = 0; nt < 8; nt++) {
                bf16x8 b = *(const bf16x8*)&Bs[nt * 16 + c][ko];
                acc[0][nt] = __builtin_amdgcn_mfma_f32_16x16x32_bf16(a0, b, acc[0][nt], 0, 0, 0);
                acc[1][nt] = __builtin_amdgcn_mfma_f32_16x16x32_bf16(a1, b, acc[1][nt], 0, 0, 0);
            }
        }
    }
#pragma unroll
    for (int it = 0; it < 2; it++)
#pragma unroll
        for (int nt = 0; nt < 8; nt++)
#pragma unroll
            for (int r = 0; r < 4; r++) {
                int i = i0 + w * 32 + it * 16 + g * 4 + r;
                int n = n0 + nt * 16 + c;
                U[(size_t)i * 16384 + n] = (short)f2bf(acc[it][nt][r]);
            }
}

// ---------------- phase2 MFMA: grid (2 jb, 1024 i) — adjacent blocks share U_i ---------
__global__ __launch_bounds__(256) void k_p2(const short* __restrict__ hb,
    const short* __restrict__ U, const float* __restrict__ cvec,
    const float* __restrict__ Wm2, const float* __restrict__ bm2,
    float* __restrict__ out)
{
    __shared__ __align__(16) short Us[128][128];   // row stride 256B, XOR swizzle
    __shared__ float cvs[128];
    __shared__ float w2s[128][4];
    int tid = threadIdx.x;
    int jb = blockIdx.x;          // 0..1
    int i = blockIdx.y;
    int b = i >> 8;
    int w = tid >> 6, lane = tid & 63, c = lane & 15, g = lane >> 4;
    if (tid < 128) {
        cvs[tid] = cvec[tid];
        *(float4*)&w2s[tid][0] = *(const float4*)&Wm2[tid * 4];
    }
    bf16x8 hf[2][4];
    {
        const short* hrow = hb + (size_t)(b * 256 + jb * 128 + w * 32 + c) * 128;
#pragma unroll
        for (int jt = 0; jt < 2; jt++)
#pragma unroll
            for (int kq = 0; kq < 4; kq++)
                hf[jt][kq] = *(const bf16x8*)(hrow + jt * 16 * 128 + kq * 32 + g * 8);
    }
    for (int idx = tid; idx < 2048; idx += 256) {
        int r = idx >> 4, s = idx & 15;
        int col = (s * 8) ^ ((r & 7) << 3);
        *(int4*)&Us[r][col] = *(const int4*)&U[(size_t)i * 16384 + r * 128 + s * 8];
    }
    __syncthreads();
    f32x4 acc[2][8] = {};
#pragma unroll
    for (int kq = 0; kq < 4; kq++) {
        int ko = kq * 32 + g * 8;
#pragma unroll
        for (int mt = 0; mt < 8; mt++) {
            int row = mt * 16 + c;
            int col = ko ^ ((row & 7) << 3);
            bf16x8 uv = *(const bf16x8*)&Us[row][col];
            acc[0][mt] = __builtin_amdgcn_mfma_f32_16x16x32_bf16(uv, hf[0][kq], acc[0][mt], 0, 0, 0);
            acc[1][mt] = __builtin_amdgcn_mfma_f32_16x16x32_bf16(uv, hf[1][kq], acc[1][mt], 0, 0, 0);
        }
    }
    float4 bmv = *(const float4*)&bm2[0];
#pragma unroll
    for (int jt = 0; jt < 2; jt++) {
        float p0 = 0.f, p1 = 0.f, p2 = 0.f, p3 = 0.f;
#pragma unroll
        for (int mt = 0; mt < 8; mt++) {
#pragma unroll
            for (int r = 0; r < 4; r++) {
                int m = mt * 16 + g * 4 + r;
                float y = acc[jt][mt][r] + cvs[m];
                float sv = y * frcp(1.f + __expf(-y));
                p0 += sv * w2s[m][0]; p1 += sv * w2s[m][1];
                p2 += sv * w2s[m][2]; p3 += sv * w2s[m][3];
            }
        }
        p0 += __shfl_xor(p0, 16, 64); p1 += __shfl_xor(p1, 16, 64);
        p2 += __shfl_xor(p2, 16, 64); p3 += __shfl_xor(p3, 16, 64);
        p0 += __shfl_xor(p0, 32, 64); p1 += __shfl_xor(p1, 32, 64);
        p2 += __shfl_xor(p2, 32, 64); p3 += __shfl_xor(p3, 32, 64);
        if (g == 0) {
            int j = jb * 128 + w * 32 + jt * 16 + c;
            float4 o4 = { p0 + bmv.x, p1 + bmv.y, p2 + bmv.z, p3 + bmv.w };
            *(float4*)&out[((size_t)i * 256 + j) * 4] = o4;
        }
    }
}

extern "C" void kernel_launch(void* const* d_in, const int* in_sizes, int n_in,
                              void* d_out, int out_size, void* d_ws, size_t ws_size,
                              hipStream_t stream)
{
    const float* x   = (const float*)d_in[0];
    const int*   ei  = (const int*)d_in[1];
    const void*  tptr= d_in[3];
    const float* tm  = (const float*)d_in[4];
    const float* Wn  = (const float*)d_in[5];
    const float* bn  = (const float*)d_in[6];
    const float* Wee = (const float*)d_in[7];
    const float* bee = (const float*)d_in[8];
    const float* Wt1 = (const float*)d_in[9];
    const float* bt1 = (const float*)d_in[10];
    const float* Wt2 = (const float*)d_in[11];
    const float* bt2 = (const float*)d_in[12];
    const float* Wa  = (const float*)d_in[13];
    const float* ba  = (const float*)d_in[14];
    const float* Wq  = (const float*)d_in[15];
    const float* bq  = (const float*)d_in[16];
    const float* Wk  = (const float*)d_in[17];
    const float* bk  = (const float*)d_in[18];
    const float* Wv  = (const float*)d_in[19];
    const float* bv  = (const float*)d_in[20];
    const float* We  = (const float*)d_in[21];
    const float* Wsk = (const float*)d_in[22];
    const float* bsk = (const float*)d_in[23];
    const float* Wf1 = (const float*)d_in[24];
    const float* bf1 = (const float*)d_in[25];
    const float* Wf2 = (const float*)d_in[26];
    const float* bf2 = (const float*)d_in[27];
    const float* Wb  = (const float*)d_in[28];
    const float* bb  = (const float*)d_in[29];
    const float* Wm1 = (const float*)d_in[30];
    const float* bm1 = (const float*)d_in[31];
    const float* Wm2 = (const float*)d_in[32];
    const float* bm2 = (const float*)d_in[33];
    float* out = (float*)d_out;
    float* ws = (float*)d_ws;

    float* h    = ws + OFF_H;
    float* qb   = ws + OFF_Q;
    short* kb16 = (short*)(ws + OFF_K);
    short* vb16 = (short*)(ws + OFF_V);
    float* skp  = ws + OFF_SKP;
    float* ss   = ws + OFF_SS;
    float* ea   = ws + OFF_EA;
    float* cvec = ws + OFF_CVEC;
    int* iws    = (int*)(ws + OFF_INT);
    int* deg    = iws;
    int* cursor = iws + 1024;
    int* rowptr = iws + 2048;
    int* eorder = iws + 3073;
    int* src_csr   = (int*)(ws + OFF_G);
    float* ea_csr  = ws + OFF_G + 65536;
    float* Mst  = ws + OFF_M;
    short* Ub   = (short*)(ws + OFF_U);
    short* Mtb  = (short*)(ws + OFF_MT);
    short* hbb  = (short*)(ws + OFF_HB);
    short* WT   = (short*)(ws + OFF_WB);

    hipMemsetAsync(deg, 0, 2048 * sizeof(int), stream);
    k_setup_all<<<1104, 256, 0, stream>>>(tptr, Wt1, bt1, Wt2, bt2, bb, Wm1, bm1, Wa, ba,
                                          ss, cvec, Wq, Wk, Wv, Wsk, Wf1, Wf2, WT,
                                          x, Wn, bn, h, ei, tm, Wee, bee, ea, deg, Wb, Mst);
    k_scan<<<1, 1024, 0, stream>>>(deg, rowptr);
    k_scatter<<<256, 256, 0, stream>>>(ei, rowptr, cursor, eorder);
    k_sort2<<<1024, 128, 0, stream>>>(rowptr, eorder, ei, ea, src_csr, ea_csr);

    for (int l = 0; l < LAYERS; l++) {
        const float* ssl = ss + l * 512;
        k_qkvs<<<64, 256, 0, stream>>>(h, ssl, WT, l,
            bq + l * 128, bk + l * 128, bv + l * 128, bsk + l * 128,
            qb, kb16, vb16, skp);
        k_attn<<<1024, 256, 0, stream>>>(qb, kb16, vb16, skp, h, src_csr, ea_csr,
                                         We + l * 128, rowptr);
        k_ffn<<<64, 256, 0, stream>>>(h, WT, l, bf1 + l * 256, bf2 + l * 128,
                                      ssl + 256, hbb, l == LAYERS - 1);
    }

    k_mtrans<<<256, 256, 0, stream>>>(Mst, Mtb);
    k_p1<<<dim3(8, 128), 256, 0, stream>>>(hbb, Mtb, Ub);
    k_p2<<<dim3(2, 1024), 256, 0, stream>>>(hbb, Ub, cvec, Wm2, bm2, out);
}

// Round 15
// 254.118 us; speedup vs baseline: 1.0872x; 1.0284x over previous
//
#include <hip/hip_runtime.h>
#include <math.h>

#define N_NODES 1024
#define HDIM 128
#define EDGES 65536
#define LAYERS 6

typedef __attribute__((ext_vector_type(8))) short bf16x8;
typedef __attribute__((ext_vector_type(4))) float f32x4;

// workspace float offsets
#define OFF_H     0
#define OFF_Q     131072
#define OFF_K     262144       // bf16 k [1024][128] (as short*)
#define OFF_V     393216       // bf16 v [1024][128] (as short*)
#define OFF_SKP   524288
#define OFF_G     655360       // src_csr (int E) + ea_csr (float E)
#define OFF_SS    917504
#define OFF_EA    920576
#define OFF_CVEC  986112
#define OFF_INT   986240
#define OFF_M     1054912      // fp32 M [128 k][16384 n], n = m*128 + l  (m-outer!)
#define OFF_U     3152064      // bf16 U [1024 i][16384 n]
#define OFF_MT    11540672     // bf16 Mt [16384 n][128 k]
#define OFF_HB    12589248     // bf16 hb [1024][128]
#define OFF_WB    12654912     // bf16 transposed weights + Wm1T

#define WM1T_OFF  786432       // short offset of Wm1T inside WT (layout compat)

__device__ __forceinline__ float silu_f(float x) { return x / (1.f + expf(-x)); }
__device__ __forceinline__ float frcp(float x) { return __builtin_amdgcn_rcpf(x); }

__device__ __forceinline__ unsigned short f2bf(float f) {
    unsigned int u = __float_as_uint(f);
    u += 0x7FFFu + ((u >> 16) & 1u);
    return (unsigned short)(u >> 16);
}
__device__ __forceinline__ float bf2f(unsigned short s) {
    return __uint_as_float(((unsigned int)s) << 16);
}

// =====================================================================================
// mega setup: blocks 0..11 ssf | 12..207 wtrans | 208..975 inpedge | 976..1103 mprep
// =====================================================================================
__global__ __launch_bounds__(256) void k_setup_all(const void* tptr,
    const float* __restrict__ Wt1, const float* __restrict__ bt1,
    const float* __restrict__ Wt2, const float* __restrict__ bt2,
    const float* __restrict__ bb, const float* __restrict__ Wm1, const float* __restrict__ bm1,
    const float* __restrict__ Wa, const float* __restrict__ ba,
    float* __restrict__ ss_all, float* __restrict__ cvec,
    const float* __restrict__ Wq, const float* __restrict__ Wk,
    const float* __restrict__ Wv, const float* __restrict__ Wsk,
    const float* __restrict__ Wf1, const float* __restrict__ Wf2,
    short* __restrict__ WT,
    const float* __restrict__ x, const float* __restrict__ Wn, const float* __restrict__ bn,
    float* __restrict__ h, const int* __restrict__ ei, const float* __restrict__ tm,
    const float* __restrict__ Wee, const float* __restrict__ bee,
    float* __restrict__ ea, int* __restrict__ deg,
    const float* __restrict__ Wb, float* __restrict__ M)
{
    __shared__ __align__(16) char smem[69632];
    int bid = blockIdx.x;
    int tid = threadIdx.x;

    if (bid < 12) {
        float* emb_s  = (float*)smem;            // 256
        float* part   = emb_s + 256;             // 2*128
        float* tmp1_s = part + 256;              // 128
        float* tmod_s = tmp1_s + 128;            // 128
        int iv = *(const int*)tptr;
        float fv = __int_as_float(iv);
        float tval = (iv > -1000000 && iv < 1000000) ? (float)iv : fv;
        {
            int fi = tid & 127;
            float fr = expf(-logf(10000.f) * (float)fi / 128.f);
            float ta = tval * fr;
            emb_s[tid] = (tid < 128) ? cosf(ta) : sinf(ta);
        }
        __syncthreads();
        {
            int col = tid & 127, sl = tid >> 7;
            float p = 0.f;
#pragma unroll 8
            for (int i = sl * 128; i < sl * 128 + 128; i++) p += emb_s[i] * Wt1[i * 128 + col];
            part[sl * 128 + col] = p;
        }
        __syncthreads();
        if (tid < 128) tmp1_s[tid] = silu_f(bt1[tid] + part[tid] + part[128 + tid]);
        __syncthreads();
        {
            int col = tid & 127, sl = tid >> 7;
            float p = 0.f;
#pragma unroll 8
            for (int i = sl * 64; i < sl * 64 + 64; i++) p += tmp1_s[i] * Wt2[i * 128 + col];
            part[sl * 128 + col] = p;
        }
        __syncthreads();
        if (tid < 128) tmod_s[tid] = silu_f(bt2[tid] + part[tid] + part[128 + tid]);
        __syncthreads();
        {
            int idx = bid * 256 + tid;       // < 3072
            int l = idx >> 9, j = idx & 511;
            float a = ba[l * 512 + j];
            const float* w = Wa + l * 65536 + j;
#pragma unroll 4
            for (int k = 0; k < 128; k++) a += tmod_s[k] * w[k * 512];
            ss_all[idx] = a;
        }
        if (bid == 0) {
            {
                int col = tid & 127, sl = tid >> 7;
                float p = 0.f;
#pragma unroll 8
                for (int i = sl * 64; i < sl * 64 + 64; i++) p += bb[i] * Wm1[i * 128 + col];
                part[sl * 128 + col] = p;
            }
            __syncthreads();
            if (tid < 128) cvec[tid] = bm1[tid] + part[tid] + part[128 + tid];
        }
    } else if (bid < 208) {
        short (*T)[80] = (short(*)[80])smem;
        int t = bid - 12;
        const float* src; short* dst; int K, N, kt, nt;
        if (t < 96) {
            int mat = t >> 2, sub = t & 3;
            int l = mat >> 2, m = mat & 3;
            src = (m == 0 ? Wq : m == 1 ? Wk : m == 2 ? Wv : Wsk) + l * 16384;
            dst = WT + (size_t)mat * 16384;
            K = 128; N = 128; kt = sub >> 1; nt = sub & 1;
        } else if (t < 144) {
            int i = t - 96; int l = i >> 3, sub = i & 7;
            src = Wf1 + l * 32768;
            dst = WT + 24 * 16384 + (size_t)l * 32768;
            K = 128; N = 256; kt = sub & 1; nt = sub >> 1;
        } else if (t < 192) {
            int i = t - 144; int l = i >> 3, sub = i & 7;
            src = Wf2 + l * 32768;
            dst = WT + 24 * 16384 + 6 * 32768 + (size_t)l * 32768;
            K = 256; N = 128; kt = sub >> 1; nt = sub & 1;
        } else {
            int sub = t - 192;
            src = Wm1;
            dst = WT + WM1T_OFF;
            K = 128; N = 128; kt = sub >> 1; nt = sub & 1;
        }
        int k0 = kt * 64, n0 = nt * 64;
        for (int p = 0; p < 16; p++) {
            int idx = p * 256 + tid;
            int kk = idx >> 6, nn = idx & 63;
            T[nn][kk] = (short)f2bf(src[(k0 + kk) * N + n0 + nn]);
        }
        __syncthreads();
        for (int p = 0; p < 2; p++) {
            int idx = p * 256 + tid;
            int nn = idx >> 3, sq = idx & 7;
            *(int4*)&dst[(size_t)(n0 + nn) * K + k0 + sq * 8] = *(const int4*)&T[nn][sq * 8];
        }
    } else if (bid < 976) {
        int b2 = bid - 208;
        if (b2 < 512) {
            int idx = b2 * 256 + tid;  // < 131072
            int i = idx >> 7, j = idx & 127;
            float acc = bn[j];
#pragma unroll
            for (int kk = 0; kk < 5; kk++) acc += x[i * 5 + kk] * Wn[kk * 128 + j];
            h[idx] = acc;
        } else {
            int e = (b2 - 512) * 256 + tid;
            int s = ei[e], d = ei[EDGES + e];
            ea[e] = tm[s * N_NODES + d] * Wee[0] + bee[0];
            atomicAdd(&deg[d], 1);
        }
    } else {
        short (*Bls)[136]   = (short(*)[136])smem;            // [l][o]
        short (*Wm1Tl)[136] = (short(*)[136])(smem + 34816);  // [m][o]
        int k = bid - 976;
        {
            int lq = (tid & 31) * 4;
            int ob = tid >> 5;  // 0..7
            for (int it = 0; it < 16; it++) {
                int o = it * 8 + ob;
                float4 vv = *(const float4*)&Wb[(size_t)o * 16384 + k * 128 + lq];
                Bls[lq][o]     = (short)f2bf(vv.x);
                Bls[lq + 1][o] = (short)f2bf(vv.y);
                Bls[lq + 2][o] = (short)f2bf(vv.z);
                Bls[lq + 3][o] = (short)f2bf(vv.w);
            }
        }
        {
            int m = tid & 127;
            int oh = tid >> 7;   // 0..1
            for (int it = 0; it < 64; it++) {
                int o = it * 2 + oh;
                Wm1Tl[m][o] = (short)f2bf(Wm1[o * 128 + m]);
            }
        }
        __syncthreads();
        int w = tid >> 6, lane = tid & 63, c = lane & 15, g = lane >> 4;
        f32x4 acc[2][8] = {};
#pragma unroll
        for (int kq = 0; kq < 4; kq++) {
            int ko = kq * 32 + g * 8;
            bf16x8 a0 = *(const bf16x8*)&Wm1Tl[w * 32 + c][ko];
            bf16x8 a1 = *(const bf16x8*)&Wm1Tl[w * 32 + 16 + c][ko];
#pragma unroll
            for (int nt = 0; nt < 8; nt++) {
                bf16x8 b = *(const bf16x8*)&Bls[nt * 16 + c][ko];
                acc[0][nt] = __builtin_amdgcn_mfma_f32_16x16x32_bf16(a0, b, acc[0][nt], 0, 0, 0);
                acc[1][nt] = __builtin_amdgcn_mfma_f32_16x16x32_bf16(a1, b, acc[1][nt], 0, 0, 0);
            }
        }
        float* Mk = M + (size_t)k * 16384;
#pragma unroll
        for (int it = 0; it < 2; it++)
#pragma unroll
            for (int nt = 0; nt < 8; nt++)
#pragma unroll
                for (int r = 0; r < 4; r++) {
                    int m = w * 32 + it * 16 + g * 4 + r;
                    int l = nt * 16 + c;
                    Mk[m * 128 + l] = acc[it][nt][r];
                }
    }
}

__global__ __launch_bounds__(1024) void k_scan(const int* __restrict__ deg, int* __restrict__ rowptr)
{
    __shared__ int tmp[1024];
    int tid = threadIdx.x;
    tmp[tid] = deg[tid];
    __syncthreads();
    for (int off = 1; off < 1024; off <<= 1) {
        int vv = (tid >= off) ? tmp[tid - off] : 0;
        __syncthreads();
        tmp[tid] += vv;
        __syncthreads();
    }
    rowptr[tid + 1] = tmp[tid];
    if (tid == 0) rowptr[0] = 0;
}

__global__ __launch_bounds__(256) void k_scatter(const int* __restrict__ ei,
    const int* __restrict__ rowptr, int* __restrict__ cursor, int* __restrict__ eorder)
{
    int e = blockIdx.x * 256 + threadIdx.x;
    int d = ei[EDGES + e];
    int pos = atomicAdd(&cursor[d], 1);
    eorder[rowptr[d] + pos] = e;
}

// ---------------- per-node bitonic sort + CSR flatten (fused) ----------------
__global__ __launch_bounds__(128) void k_sort2(const int* __restrict__ rowptr,
    int* __restrict__ eorder, const int* __restrict__ ei, const float* __restrict__ ea,
    int* __restrict__ src_csr, float* __restrict__ ea_csr)
{
    __shared__ int key[256];
    int node = blockIdx.x;
    int tid = threadIdx.x;
    int beg = rowptr[node], end = rowptr[node + 1];
    int n = end - beg;
    if (n <= 256) {
        for (int i = tid; i < 256; i += 128) key[i] = (i < n) ? eorder[beg + i] : 0x7FFFFFFF;
        __syncthreads();
        for (int k = 2; k <= 256; k <<= 1) {
            for (int j = k >> 1; j > 0; j >>= 1) {
                int i = ((tid / j) * 2 * j) + (tid % j);
                int l = i + j;
                bool up = ((i & k) == 0);
                int a = key[i], b = key[l];
                if ((a > b) == up) { key[i] = b; key[l] = a; }
                __syncthreads();
            }
        }
        for (int i = tid; i < n; i += 128) {
            int e = key[i];
            src_csr[beg + i] = ei[e];
            ea_csr[beg + i] = ea[e];
        }
    } else {
        if (tid == 0) {
            for (int i = beg + 1; i < end; ++i) {
                int kk = eorder[i];
                int j = i - 1;
                while (j >= beg && eorder[j] > kk) { eorder[j + 1] = eorder[j]; --j; }
                eorder[j + 1] = kk;
            }
        }
        __syncthreads();
        for (int i = tid; i < n; i += 128) {
            int e = eorder[beg + i];
            src_csr[beg + i] = ei[e];
            ea_csr[beg + i] = ea[e];
        }
    }
}

// ---------------- MFMA qkvs (standalone, layer 0): 16 rows/block, wave-per-mat --------
__global__ __launch_bounds__(256) void k_qkvs(const float* __restrict__ h,
    const float* __restrict__ ss, const short* __restrict__ WT, int layer,
    const float* __restrict__ bq, const float* __restrict__ bk,
    const float* __restrict__ bv, const float* __restrict__ bsk,
    float* __restrict__ q, short* __restrict__ kb16, short* __restrict__ vb16,
    float* __restrict__ skp)
{
    __shared__ __align__(16) short As[16][136];
    __shared__ float shs[128], scs[128];
    int tid = threadIdx.x;
    int r0 = blockIdx.x * 16;
    if (tid < 128) { shs[tid] = ss[tid]; scs[tid] = ss[128 + tid]; }
    __syncthreads();
    {
        int row = tid >> 4, o = tid & 15;
        const float* hr = h + (size_t)(r0 + row) * 128 + o * 8;
        float s = 0.f, s2 = 0.f;
#pragma unroll
        for (int j = 0; j < 2; j++) {
            float4 vv = *(const float4*)&hr[j * 4];
            s += vv.x + vv.y + vv.z + vv.w;
            s2 += vv.x * vv.x + vv.y * vv.y + vv.z * vv.z + vv.w * vv.w;
        }
        s += __shfl_xor(s, 1, 64); s2 += __shfl_xor(s2, 1, 64);
        s += __shfl_xor(s, 2, 64); s2 += __shfl_xor(s2, 2, 64);
        s += __shfl_xor(s, 4, 64); s2 += __shfl_xor(s2, 4, 64);
        s += __shfl_xor(s, 8, 64); s2 += __shfl_xor(s2, 8, 64);
        float mu = s * (1.f / 128.f);
        float var = s2 * (1.f / 128.f) - mu * mu;
        float rs = rsqrtf(var + 1e-5f);
#pragma unroll
        for (int j = 0; j < 2; j++) {
            float4 vv = *(const float4*)&hr[j * 4];
            int cb = o * 8 + j * 4;
            short4 o4;
            o4.x = (short)f2bf((vv.x - mu) * rs * (1.f + scs[cb])     + shs[cb]);
            o4.y = (short)f2bf((vv.y - mu) * rs * (1.f + scs[cb + 1]) + shs[cb + 1]);
            o4.z = (short)f2bf((vv.z - mu) * rs * (1.f + scs[cb + 2]) + shs[cb + 2]);
            o4.w = (short)f2bf((vv.w - mu) * rs * (1.f + scs[cb + 3]) + shs[cb + 3]);
            *(short4*)&As[row][cb] = o4;
        }
    }
    __syncthreads();
    int w = tid >> 6, lane = tid & 63, c = lane & 15, g = lane >> 4;
    const short* Wm = WT + (size_t)(layer * 4 + w) * 16384;
    f32x4 acc[8] = {};
#pragma unroll
    for (int kq = 0; kq < 4; kq++) {
        int ko = kq * 32 + g * 8;
        bf16x8 a0 = *(const bf16x8*)&As[c][ko];
#pragma unroll
        for (int nt = 0; nt < 8; nt++) {
            bf16x8 bfr = *(const bf16x8*)&Wm[(size_t)(nt * 16 + c) * 128 + ko];
            acc[nt] = __builtin_amdgcn_mfma_f32_16x16x32_bf16(a0, bfr, acc[nt], 0, 0, 0);
        }
    }
    if (w == 0) {
#pragma unroll
        for (int nt = 0; nt < 8; nt++) {
            int n = nt * 16 + c;
            float bv2 = bq[n];
#pragma unroll
            for (int r = 0; r < 4; r++)
                q[(size_t)(r0 + g * 4 + r) * 128 + n] = acc[nt][r] + bv2;
        }
    } else if (w == 1) {
#pragma unroll
        for (int nt = 0; nt < 8; nt++) {
            int n = nt * 16 + c;
            float bv2 = bk[n];
#pragma unroll
            for (int r = 0; r < 4; r++)
                kb16[(size_t)(r0 + g * 4 + r) * 128 + n] = (short)f2bf(acc[nt][r] + bv2);
        }
    } else if (w == 2) {
#pragma unroll
        for (int nt = 0; nt < 8; nt++) {
            int n = nt * 16 + c;
            float bv2 = bv[n];
#pragma unroll
            for (int r = 0; r < 4; r++)
                vb16[(size_t)(r0 + g * 4 + r) * 128 + n] = (short)f2bf(acc[nt][r] + bv2);
        }
    } else {
#pragma unroll
        for (int nt = 0; nt < 8; nt++) {
            int n = nt * 16 + c;
            float bv2 = bsk[n];
#pragma unroll
            for (int r = 0; r < 4; r++)
                skp[(size_t)(r0 + g * 4 + r) * 128 + n] = acc[nt][r] + bv2;
        }
    }
}

// ---------------- fused FFN(l) + QKVS(l+1): 16 rows/block, grid 64 --------------------
// do_qkvs=0 (last layer): skip qkvs stage, write hb instead.
__global__ __launch_bounds__(256) void k_ffnq(float* __restrict__ h,
    const short* __restrict__ WT, int layer,
    const float* __restrict__ bf1, const float* __restrict__ bf2,
    const float* __restrict__ ss2,
    int do_qkvs, const float* __restrict__ ssn,
    const float* __restrict__ bq, const float* __restrict__ bk,
    const float* __restrict__ bv, const float* __restrict__ bsk,
    float* __restrict__ q, short* __restrict__ kb16, short* __restrict__ vb16,
    float* __restrict__ skp, short* __restrict__ hb)
{
    __shared__ __align__(16) short As[16][136];
    __shared__ __align__(16) short Gs[16][264];
    __shared__ float Hs[16][132];
    __shared__ float shs[128], scs[128];
    int tid = threadIdx.x;
    int r0 = blockIdx.x * 16;
    if (tid < 128) { shs[tid] = ss2[tid]; scs[tid] = ss2[128 + tid]; }
    __syncthreads();
    {   // LN+mod (ffn) from global h
        int row = tid >> 4, o = tid & 15;
        const float* hr = h + (size_t)(r0 + row) * 128 + o * 8;
        float s = 0.f, s2 = 0.f;
#pragma unroll
        for (int j = 0; j < 2; j++) {
            float4 vv = *(const float4*)&hr[j * 4];
            s += vv.x + vv.y + vv.z + vv.w;
            s2 += vv.x * vv.x + vv.y * vv.y + vv.z * vv.z + vv.w * vv.w;
        }
        s += __shfl_xor(s, 1, 64); s2 += __shfl_xor(s2, 1, 64);
        s += __shfl_xor(s, 2, 64); s2 += __shfl_xor(s2, 2, 64);
        s += __shfl_xor(s, 4, 64); s2 += __shfl_xor(s2, 4, 64);
        s += __shfl_xor(s, 8, 64); s2 += __shfl_xor(s2, 8, 64);
        float mu = s * (1.f / 128.f);
        float var = s2 * (1.f / 128.f) - mu * mu;
        float rs = rsqrtf(var + 1e-5f);
#pragma unroll
        for (int j = 0; j < 2; j++) {
            float4 vv = *(const float4*)&hr[j * 4];
            int cb = o * 8 + j * 4;
            short4 o4;
            o4.x = (short)f2bf((vv.x - mu) * rs * (1.f + scs[cb])     + shs[cb]);
            o4.y = (short)f2bf((vv.y - mu) * rs * (1.f + scs[cb + 1]) + shs[cb + 1]);
            o4.z = (short)f2bf((vv.z - mu) * rs * (1.f + scs[cb + 2]) + shs[cb + 2]);
            o4.w = (short)f2bf((vv.w - mu) * rs * (1.f + scs[cb + 3]) + shs[cb + 3]);
            *(short4*)&As[row][cb] = o4;
        }
    }
    __syncthreads();
    int w = tid >> 6, lane = tid & 63, c = lane & 15, g = lane >> 4;
    const short* W1 = WT + 24 * 16384 + (size_t)layer * 32768;
    const short* W2 = WT + 24 * 16384 + 6 * 32768 + (size_t)layer * 32768;
    {   // f1 + gelu
        f32x4 acc[4] = {};
#pragma unroll
        for (int kq = 0; kq < 4; kq++) {
            int ko = kq * 32 + g * 8;
            bf16x8 a0 = *(const bf16x8*)&As[c][ko];
#pragma unroll
            for (int nt = 0; nt < 4; nt++) {
                bf16x8 bfr = *(const bf16x8*)&W1[(size_t)(w * 64 + nt * 16 + c) * 128 + ko];
                acc[nt] = __builtin_amdgcn_mfma_f32_16x16x32_bf16(a0, bfr, acc[nt], 0, 0, 0);
            }
        }
#pragma unroll
        for (int nt = 0; nt < 4; nt++) {
            int n = w * 64 + nt * 16 + c;
            float bv = bf1[n];
#pragma unroll
            for (int r = 0; r < 4; r++) {
                float y = acc[nt][r] + bv;
                float gl = 0.5f * y * (1.f + erff(y * 0.70710678118654752f));
                Gs[g * 4 + r][n] = (short)f2bf(gl);
            }
        }
    }
    __syncthreads();
    {   // f2 + residual: write h global AND Hs LDS (and hb if last layer)
        f32x4 acc2[2] = {};
#pragma unroll
        for (int kq = 0; kq < 8; kq++) {
            int ko = kq * 32 + g * 8;
            bf16x8 a0 = *(const bf16x8*)&Gs[c][ko];
#pragma unroll
            for (int nt2 = 0; nt2 < 2; nt2++) {
                bf16x8 bfr = *(const bf16x8*)&W2[(size_t)(w * 32 + nt2 * 16 + c) * 256 + ko];
                acc2[nt2] = __builtin_amdgcn_mfma_f32_16x16x32_bf16(a0, bfr, acc2[nt2], 0, 0, 0);
            }
        }
#pragma unroll
        for (int nt2 = 0; nt2 < 2; nt2++) {
            int n = w * 32 + nt2 * 16 + c;
            float bv = bf2[n];
#pragma unroll
            for (int r = 0; r < 4; r++) {
                int lr = g * 4 + r;
                float nv = h[(size_t)(r0 + lr) * 128 + n] + acc2[nt2][r] + bv;
                h[(size_t)(r0 + lr) * 128 + n] = nv;
                Hs[lr][n] = nv;
                if (!do_qkvs) hb[(size_t)(r0 + lr) * 128 + n] = (short)f2bf(nv);
            }
        }
    }
    if (!do_qkvs) return;
    __syncthreads();
    // reload shs/scs with next layer's msa modulation
    if (tid < 128) { shs[tid] = ssn[tid]; scs[tid] = ssn[128 + tid]; }
    __syncthreads();
    {   // LN+mod (next layer qkvs) from Hs
        int row = tid >> 4, o = tid & 15;
        float vals[8];
#pragma unroll
        for (int j = 0; j < 8; j++) vals[j] = Hs[row][o * 8 + j];
        float s = 0.f, s2 = 0.f;
#pragma unroll
        for (int j = 0; j < 8; j++) { s += vals[j]; s2 += vals[j] * vals[j]; }
        s += __shfl_xor(s, 1, 64); s2 += __shfl_xor(s2, 1, 64);
        s += __shfl_xor(s, 2, 64); s2 += __shfl_xor(s2, 2, 64);
        s += __shfl_xor(s, 4, 64); s2 += __shfl_xor(s2, 4, 64);
        s += __shfl_xor(s, 8, 64); s2 += __shfl_xor(s2, 8, 64);
        float mu = s * (1.f / 128.f);
        float var = s2 * (1.f / 128.f) - mu * mu;
        float rs = rsqrtf(var + 1e-5f);
#pragma unroll
        for (int j = 0; j < 8; j++) {
            int cb = o * 8 + j;
            As[row][cb] = (short)f2bf((vals[j] - mu) * rs * (1.f + scs[cb]) + shs[cb]);
        }
    }
    __syncthreads();
    {   // qkvs MFMA: wave-per-mat, layer+1 weights
        const short* Wm = WT + (size_t)((layer + 1) * 4 + w) * 16384;
        f32x4 acc[8] = {};
#pragma unroll
        for (int kq = 0; kq < 4; kq++) {
            int ko = kq * 32 + g * 8;
            bf16x8 a0 = *(const bf16x8*)&As[c][ko];
#pragma unroll
            for (int nt = 0; nt < 8; nt++) {
                bf16x8 bfr = *(const bf16x8*)&Wm[(size_t)(nt * 16 + c) * 128 + ko];
                acc[nt] = __builtin_amdgcn_mfma_f32_16x16x32_bf16(a0, bfr, acc[nt], 0, 0, 0);
            }
        }
        if (w == 0) {
#pragma unroll
            for (int nt = 0; nt < 8; nt++) {
                int n = nt * 16 + c;
                float bv2 = bq[n];
#pragma unroll
                for (int r = 0; r < 4; r++)
                    q[(size_t)(r0 + g * 4 + r) * 128 + n] = acc[nt][r] + bv2;
            }
        } else if (w == 1) {
#pragma unroll
            for (int nt = 0; nt < 8; nt++) {
                int n = nt * 16 + c;
                float bv2 = bk[n];
#pragma unroll
                for (int r = 0; r < 4; r++)
                    kb16[(size_t)(r0 + g * 4 + r) * 128 + n] = (short)f2bf(acc[nt][r] + bv2);
            }
        } else if (w == 2) {
#pragma unroll
            for (int nt = 0; nt < 8; nt++) {
                int n = nt * 16 + c;
                float bv2 = bv[n];
#pragma unroll
                for (int r = 0; r < 4; r++)
                    vb16[(size_t)(r0 + g * 4 + r) * 128 + n] = (short)f2bf(acc[nt][r] + bv2);
            }
        } else {
#pragma unroll
            for (int nt = 0; nt < 8; nt++) {
                int n = nt * 16 + c;
                float bv2 = bsk[n];
#pragma unroll
                for (int r = 0; r < 4; r++)
                    skp[(size_t)(r0 + g * 4 + r) * 128 + n] = acc[nt][r] + bv2;
            }
        }
    }
}

// ---------------- attention: 4 waves per node, bf16 k/v gathers, LDS 4-way merge ------
__global__ __launch_bounds__(256) void k_attn(const float* __restrict__ q,
    const short* __restrict__ kb16, const short* __restrict__ vb16,
    const float* __restrict__ skp, float* __restrict__ h,
    const int* __restrict__ src_csr, const float* __restrict__ ea_csr,
    const float* __restrict__ We_l, const int* __restrict__ rowptr)
{
    __shared__ float ms[3][64], ssb[3][64], a0s[3][64], a1s[3][64];
    int tid = threadIdx.x;
    int wid = tid >> 6;            // 0..3 = quarter
    int lane = tid & 63;
    int node = blockIdx.x;
    int c0 = lane * 2;
    float2 q2 = *(const float2*)&q[node * 128 + c0];
    float we0 = We_l[c0], we1 = We_l[c0 + 1];
    int beg = rowptr[node], end = rowptr[node + 1];
    int n = end - beg;
    int tb = beg + (n * wid) / 4;
    int te = beg + (n * (wid + 1)) / 4;
    float m = -INFINITY, s = 0.f, a0 = 0.f, a1 = 0.f;
    const float isc = 0.17677669529663687f;  // 1/sqrt(32)

    int t = tb;
    for (; t + 3 < te; t += 4) {
        int sn0 = src_csr[t],     sn1 = src_csr[t + 1];
        int sn2 = src_csr[t + 2], sn3 = src_csr[t + 3];
        float e0 = ea_csr[t],     e1 = ea_csr[t + 1];
        float e2 = ea_csr[t + 2], e3 = ea_csr[t + 3];
        ushort2 ku0 = *(const ushort2*)&kb16[sn0 * 128 + c0];
        ushort2 ku1 = *(const ushort2*)&kb16[sn1 * 128 + c0];
        ushort2 ku2 = *(const ushort2*)&kb16[sn2 * 128 + c0];
        ushort2 ku3 = *(const ushort2*)&kb16[sn3 * 128 + c0];
        ushort2 vu0 = *(const ushort2*)&vb16[sn0 * 128 + c0];
        ushort2 vu1 = *(const ushort2*)&vb16[sn1 * 128 + c0];
        ushort2 vu2 = *(const ushort2*)&vb16[sn2 * 128 + c0];
        ushort2 vu3 = *(const ushort2*)&vb16[sn3 * 128 + c0];
        float p0 = q2.x * (bf2f(ku0.x) + e0 * we0) + q2.y * (bf2f(ku0.y) + e0 * we1);
        float p1 = q2.x * (bf2f(ku1.x) + e1 * we0) + q2.y * (bf2f(ku1.y) + e1 * we1);
        float p2 = q2.x * (bf2f(ku2.x) + e2 * we0) + q2.y * (bf2f(ku2.y) + e2 * we1);
        float p3 = q2.x * (bf2f(ku3.x) + e3 * we0) + q2.y * (bf2f(ku3.y) + e3 * we1);
        p0 += __shfl_xor(p0, 1, 16); p1 += __shfl_xor(p1, 1, 16);
        p2 += __shfl_xor(p2, 1, 16); p3 += __shfl_xor(p3, 1, 16);
        p0 += __shfl_xor(p0, 2, 16); p1 += __shfl_xor(p1, 2, 16);
        p2 += __shfl_xor(p2, 2, 16); p3 += __shfl_xor(p3, 2, 16);
        p0 += __shfl_xor(p0, 4, 16); p1 += __shfl_xor(p1, 4, 16);
        p2 += __shfl_xor(p2, 4, 16); p3 += __shfl_xor(p3, 4, 16);
        p0 += __shfl_xor(p0, 8, 16); p1 += __shfl_xor(p1, 8, 16);
        p2 += __shfl_xor(p2, 8, 16); p3 += __shfl_xor(p3, 8, 16);
        {
            float al = p0 * isc;
            float mn = fmaxf(m, al);
            float scale = __expf(m - mn), wq = __expf(al - mn);
            s = s * scale + wq;
            a0 = a0 * scale + wq * (bf2f(vu0.x) + e0 * we0);
            a1 = a1 * scale + wq * (bf2f(vu0.y) + e0 * we1);
            m = mn;
        }
        {
            float al = p1 * isc;
            float mn = fmaxf(m, al);
            float scale = __expf(m - mn), wq = __expf(al - mn);
            s = s * scale + wq;
            a0 = a0 * scale + wq * (bf2f(vu1.x) + e1 * we0);
            a1 = a1 * scale + wq * (bf2f(vu1.y) + e1 * we1);
            m = mn;
        }
        {
            float al = p2 * isc;
            float mn = fmaxf(m, al);
            float scale = __expf(m - mn), wq = __expf(al - mn);
            s = s * scale + wq;
            a0 = a0 * scale + wq * (bf2f(vu2.x) + e2 * we0);
            a1 = a1 * scale + wq * (bf2f(vu2.y) + e2 * we1);
            m = mn;
        }
        {
            float al = p3 * isc;
            float mn = fmaxf(m, al);
            float scale = __expf(m - mn), wq = __expf(al - mn);
            s = s * scale + wq;
            a0 = a0 * scale + wq * (bf2f(vu3.x) + e3 * we0);
            a1 = a1 * scale + wq * (bf2f(vu3.y) + e3 * we1);
            m = mn;
        }
    }
    for (; t < te; ++t) {
        int sn = src_csr[t];
        float eav = ea_csr[t];
        ushort2 ku = *(const ushort2*)&kb16[sn * 128 + c0];
        ushort2 vu = *(const ushort2*)&vb16[sn * 128 + c0];
        float part = q2.x * (bf2f(ku.x) + eav * we0) + q2.y * (bf2f(ku.y) + eav * we1);
        part += __shfl_xor(part, 1, 16);
        part += __shfl_xor(part, 2, 16);
        part += __shfl_xor(part, 4, 16);
        part += __shfl_xor(part, 8, 16);
        float alpha = part * isc;
        float mn = fmaxf(m, alpha);
        float scale = __expf(m - mn), wq = __expf(alpha - mn);
        s = s * scale + wq;
        a0 = a0 * scale + wq * (bf2f(vu.x) + eav * we0);
        a1 = a1 * scale + wq * (bf2f(vu.y) + eav * we1);
        m = mn;
    }
    if (wid > 0) {
        ms[wid - 1][lane] = m; ssb[wid - 1][lane] = s;
        a0s[wid - 1][lane] = a0; a1s[wid - 1][lane] = a1;
    }
    __syncthreads();
    if (wid == 0) {
#pragma unroll
        for (int p = 0; p < 3; p++) {
            float mB = ms[p][lane], sB = ssb[p][lane];
            float b0 = a0s[p][lane], b1 = a1s[p][lane];
            float mm = fmaxf(m, mB);
            float eA = (m  > -1e30f) ? __expf(m  - mm) : 0.f;
            float eB = (mB > -1e30f) ? __expf(mB - mm) : 0.f;
            s = s * eA + sB * eB;
            a0 = a0 * eA + b0 * eB;
            a1 = a1 * eA + b1 * eB;
            m = mm;
        }
        float inv = (s > 0.f) ? 1.f / (s + 1e-16f) : 0.f;
        int o = node * 128 + c0;
        h[o]     += skp[o]     + a0 * inv;
        h[o + 1] += skp[o + 1] + a1 * inv;
    }
}

// ---------------- Mt[n][k] (bf16) <- M[k][n] (fp32) ----------------
__global__ __launch_bounds__(256) void k_mtrans(const float* __restrict__ M,
                                                short* __restrict__ Mt)
{
    __shared__ __align__(16) short Ts[64][136];
    int tid = threadIdx.x;
    int n0 = blockIdx.x * 64;
    for (int p = 0; p < 32; p++) {
        int idx = p * 256 + tid;
        int k = idx >> 6, nn = idx & 63;
        Ts[nn][k] = (short)f2bf(M[(size_t)k * 16384 + n0 + nn]);
    }
    __syncthreads();
    for (int p = 0; p < 4; p++) {
        int idx = p * 256 + tid;
        int nn = idx >> 4, s = idx & 15;
        *(int4*)&Mt[(size_t)(n0 + nn) * 128 + s * 8] = *(const int4*)&Ts[nn][s * 8];
    }
}

// ---------------- phase1 MFMA: grid (8 i-tiles, 128 n-tiles) for Mt L3 reuse ----------
__global__ __launch_bounds__(256) void k_p1(const short* __restrict__ hb,
    const short* __restrict__ Mt, short* __restrict__ U)
{
    __shared__ __align__(16) short As[128][72];
    __shared__ __align__(16) short Bs[128][72];
    int tid = threadIdx.x;
    int i0 = blockIdx.x * 128;
    int n0 = blockIdx.y * 128;
    int w = tid >> 6, lane = tid & 63, c = lane & 15, g = lane >> 4;
    f32x4 acc[2][8] = {};
    for (int kh = 0; kh < 2; kh++) {
        __syncthreads();
        for (int idx = tid; idx < 1024; idx += 256) {
            int r = idx >> 3, s = idx & 7;
            *(int4*)&As[r][s * 8] = *(const int4*)&hb[(i0 + r) * 128 + kh * 64 + s * 8];
            *(int4*)&Bs[r][s * 8] = *(const int4*)&Mt[(size_t)(n0 + r) * 128 + kh * 64 + s * 8];
        }
        __syncthreads();
#pragma unroll
        for (int kk = 0; kk < 2; kk++) {
            int ko = kk * 32 + g * 8;
            bf16x8 a0 = *(const bf16x8*)&As[w * 32 + c][ko];
            bf16x8 a1 = *(const bf16x8*)&As[w * 32 + 16 + c][ko];
#pragma unroll
            for (int nt = 0; nt < 8; nt++) {
                bf16x8 b = *(const bf16x8*)&Bs[nt * 16 + c][ko];
                acc[0][nt] = __builtin_amdgcn_mfma_f32_16x16x32_bf16(a0, b, acc[0][nt], 0, 0, 0);
                acc[1][nt] = __builtin_amdgcn_mfma_f32_16x16x32_bf16(a1, b, acc[1][nt], 0, 0, 0);
            }
        }
    }
#pragma unroll
    for (int it = 0; it < 2; it++)
#pragma unroll
        for (int nt = 0; nt < 8; nt++)
#pragma unroll
            for (int r = 0; r < 4; r++) {
                int i = i0 + w * 32 + it * 16 + g * 4 + r;
                int n = n0 + nt * 16 + c;
                U[(size_t)i * 16384 + n] = (short)f2bf(acc[it][nt][r]);
            }
}

// ---------------- phase2 MFMA: grid (2 jb, 1024 i) — adjacent blocks share U_i ---------
__global__ __launch_bounds__(256) void k_p2(const short* __restrict__ hb,
    const short* __restrict__ U, const float* __restrict__ cvec,
    const float* __restrict__ Wm2, const float* __restrict__ bm2,
    float* __restrict__ out)
{
    __shared__ __align__(16) short Us[128][128];   // row stride 256B, XOR swizzle
    __shared__ float cvs[128];
    __shared__ float w2s[128][4];
    int tid = threadIdx.x;
    int jb = blockIdx.x;          // 0..1
    int i = blockIdx.y;
    int b = i >> 8;
    int w = tid >> 6, lane = tid & 63, c = lane & 15, g = lane >> 4;
    if (tid < 128) {
        cvs[tid] = cvec[tid];
        *(float4*)&w2s[tid][0] = *(const float4*)&Wm2[tid * 4];
    }
    bf16x8 hf[2][4];
    {
        const short* hrow = hb + (size_t)(b * 256 + jb * 128 + w * 32 + c) * 128;
#pragma unroll
        for (int jt = 0; jt < 2; jt++)
#pragma unroll
            for (int kq = 0; kq < 4; kq++)
                hf[jt][kq] = *(const bf16x8*)(hrow + jt * 16 * 128 + kq * 32 + g * 8);
    }
    for (int idx = tid; idx < 2048; idx += 256) {
        int r = idx >> 4, s = idx & 15;
        int col = (s * 8) ^ ((r & 7) << 3);
        *(int4*)&Us[r][col] = *(const int4*)&U[(size_t)i * 16384 + r * 128 + s * 8];
    }
    __syncthreads();
    f32x4 acc[2][8] = {};
#pragma unroll
    for (int kq = 0; kq < 4; kq++) {
        int ko = kq * 32 + g * 8;
#pragma unroll
        for (int mt = 0; mt < 8; mt++) {
            int row = mt * 16 + c;
            int col = ko ^ ((row & 7) << 3);
            bf16x8 uv = *(const bf16x8*)&Us[row][col];
            acc[0][mt] = __builtin_amdgcn_mfma_f32_16x16x32_bf16(uv, hf[0][kq], acc[0][mt], 0, 0, 0);
            acc[1][mt] = __builtin_amdgcn_mfma_f32_16x16x32_bf16(uv, hf[1][kq], acc[1][mt], 0, 0, 0);
        }
    }
    float4 bmv = *(const float4*)&bm2[0];
#pragma unroll
    for (int jt = 0; jt < 2; jt++) {
        float p0 = 0.f, p1 = 0.f, p2 = 0.f, p3 = 0.f;
#pragma unroll
        for (int mt = 0; mt < 8; mt++) {
#pragma unroll
            for (int r = 0; r < 4; r++) {
                int m = mt * 16 + g * 4 + r;
                float y = acc[jt][mt][r] + cvs[m];
                float sv = y * frcp(1.f + __expf(-y));
                p0 += sv * w2s[m][0]; p1 += sv * w2s[m][1];
                p2 += sv * w2s[m][2]; p3 += sv * w2s[m][3];
            }
        }
        p0 += __shfl_xor(p0, 16, 64); p1 += __shfl_xor(p1, 16, 64);
        p2 += __shfl_xor(p2, 16, 64); p3 += __shfl_xor(p3, 16, 64);
        p0 += __shfl_xor(p0, 32, 64); p1 += __shfl_xor(p1, 32, 64);
        p2 += __shfl_xor(p2, 32, 64); p3 += __shfl_xor(p3, 32, 64);
        if (g == 0) {
            int j = jb * 128 + w * 32 + jt * 16 + c;
            float4 o4 = { p0 + bmv.x, p1 + bmv.y, p2 + bmv.z, p3 + bmv.w };
            *(float4*)&out[((size_t)i * 256 + j) * 4] = o4;
        }
    }
}

extern "C" void kernel_launch(void* const* d_in, const int* in_sizes, int n_in,
                              void* d_out, int out_size, void* d_ws, size_t ws_size,
                              hipStream_t stream)
{
    const float* x   = (const float*)d_in[0];
    const int*   ei  = (const int*)d_in[1];
    const void*  tptr= d_in[3];
    const float* tm  = (const float*)d_in[4];
    const float* Wn  = (const float*)d_in[5];
    const float* bn  = (const float*)d_in[6];
    const float* Wee = (const float*)d_in[7];
    const float* bee = (const float*)d_in[8];
    const float* Wt1 = (const float*)d_in[9];
    const float* bt1 = (const float*)d_in[10];
    const float* Wt2 = (const float*)d_in[11];
    const float* bt2 = (const float*)d_in[12];
    const float* Wa  = (const float*)d_in[13];
    const float* ba  = (const float*)d_in[14];
    const float* Wq  = (const float*)d_in[15];
    const float* bq  = (const float*)d_in[16];
    const float* Wk  = (const float*)d_in[17];
    const float* bk  = (const float*)d_in[18];
    const float* Wv  = (const float*)d_in[19];
    const float* bv  = (const float*)d_in[20];
    const float* We  = (const float*)d_in[21];
    const float* Wsk = (const float*)d_in[22];
    const float* bsk = (const float*)d_in[23];
    const float* Wf1 = (const float*)d_in[24];
    const float* bf1 = (const float*)d_in[25];
    const float* Wf2 = (const float*)d_in[26];
    const float* bf2 = (const float*)d_in[27];
    const float* Wb  = (const float*)d_in[28];
    const float* bb  = (const float*)d_in[29];
    const float* Wm1 = (const float*)d_in[30];
    const float* bm1 = (const float*)d_in[31];
    const float* Wm2 = (const float*)d_in[32];
    const float* bm2 = (const float*)d_in[33];
    float* out = (float*)d_out;
    float* ws = (float*)d_ws;

    float* h    = ws + OFF_H;
    float* qb   = ws + OFF_Q;
    short* kb16 = (short*)(ws + OFF_K);
    short* vb16 = (short*)(ws + OFF_V);
    float* skp  = ws + OFF_SKP;
    float* ss   = ws + OFF_SS;
    float* ea   = ws + OFF_EA;
    float* cvec = ws + OFF_CVEC;
    int* iws    = (int*)(ws + OFF_INT);
    int* deg    = iws;
    int* cursor = iws + 1024;
    int* rowptr = iws + 2048;
    int* eorder = iws + 3073;
    int* src_csr   = (int*)(ws + OFF_G);
    float* ea_csr  = ws + OFF_G + 65536;
    float* Mst  = ws + OFF_M;
    short* Ub   = (short*)(ws + OFF_U);
    short* Mtb  = (short*)(ws + OFF_MT);
    short* hbb  = (short*)(ws + OFF_HB);
    short* WT   = (short*)(ws + OFF_WB);

    hipMemsetAsync(deg, 0, 2048 * sizeof(int), stream);
    k_setup_all<<<1104, 256, 0, stream>>>(tptr, Wt1, bt1, Wt2, bt2, bb, Wm1, bm1, Wa, ba,
                                          ss, cvec, Wq, Wk, Wv, Wsk, Wf1, Wf2, WT,
                                          x, Wn, bn, h, ei, tm, Wee, bee, ea, deg, Wb, Mst);
    k_scan<<<1, 1024, 0, stream>>>(deg, rowptr);
    k_scatter<<<256, 256, 0, stream>>>(ei, rowptr, cursor, eorder);
    k_sort2<<<1024, 128, 0, stream>>>(rowptr, eorder, ei, ea, src_csr, ea_csr);

    // layer 0 qkvs
    k_qkvs<<<64, 256, 0, stream>>>(h, ss, WT, 0,
        bq, bk, bv, bsk, qb, kb16, vb16, skp);
    for (int l = 0; l < LAYERS; l++) {
        int nl = l + 1;
        int doq = (l < LAYERS - 1) ? 1 : 0;
        k_attn<<<1024, 256, 0, stream>>>(qb, kb16, vb16, skp, h, src_csr, ea_csr,
                                         We + l * 128, rowptr);
        k_ffnq<<<64, 256, 0, stream>>>(h, WT, l, bf1 + l * 256, bf2 + l * 128,
            ss + l * 512 + 256, doq, ss + nl * 512,
            bq + (doq ? nl : 0) * 128, bk + (doq ? nl : 0) * 128,
            bv + (doq ? nl : 0) * 128, bsk + (doq ? nl : 0) * 128,
            qb, kb16, vb16, skp, hbb);
    }

    k_mtrans<<<256, 256, 0, stream>>>(Mst, Mtb);
    k_p1<<<dim3(8, 128), 256, 0, stream>>>(hbb, Mtb, Ub);
    k_p2<<<dim3(2, 1024), 256, 0, stream>>>(hbb, Ub, cvec, Wm2, bm2, out);
}